// Round 9
// baseline (244.833 us; speedup 1.0000x reference)
//
#include <hip/hip_runtime.h>
#include <hip/hip_bf16.h>

// ModernNCA fused bf16-MFMA pipeline, v9.
// B=512 queries, N=131072 candidates, D=192, H=256, NY=10.
// v9: k_dist barrier-free — A-frags read directly from global ce (24.6 KB
// per-chunk working set is L1-resident; paired blocks + 4 waves reuse it),
// ct staging + its 8 barriers deleted; ET wave-private; one LDS union for
// ET / dense-P staging. k_encode query+cand launches merged (grid 8+2048).
typedef __bf16 bf16;
typedef __attribute__((ext_vector_type(8))) __bf16 bf16x8;
typedef __attribute__((ext_vector_type(4))) __bf16 bf16x4;
typedef __attribute__((ext_vector_type(4))) float f32x4;

#define NQ     512
#define NC     131072
#define DIM    192
#define HID    256
#define NY     10
#define NSLICE 512           // cand slices of 256; k_dist grid = 2*NSLICE

// ---------------- workspace layout (bytes) ----------------
#define OFF_W1B 0u                              // 24 planes x 256 x 8 bf16 = 98304
#define OFF_W2B (OFF_W1B + 98304u)              // 32 planes x 192 x 8 bf16 = 98304
#define OFF_XEB (OFF_W2B + 98304u)              // 24 planes x 512 x 8 bf16 = 196608
#define OFF_X2  (OFF_XEB + 196608u)             // 512 f32 = 2048
#define OFF_CE  (OFF_X2 + 2048u)                // 131072x192 bf16 = 50331648
#define OFF_C2  (OFF_CE + 50331648u)            // 131072 f32 = 524288
#define OFF_P   (OFF_C2 + 524288u)              // 1024 blocks x 256 q x 12 f32 = 12582912

// ---------------- K0: weight cast into B-fragment plane layout ----------
// Plane p = (k>>5)*4 + ((k>>3)&3); element j = k&7.
__global__ __launch_bounds__(256) void k_prep(const float* __restrict__ W1,
                                              const float* __restrict__ W2,
                                              bf16* __restrict__ W1B,
                                              bf16* __restrict__ W2B) {
  int idx = blockIdx.x * 256 + threadIdx.x;   // 0..98303
  if (idx < 192 * 256) {
    int k = idx / 256, n = idx % 256;
    int p = (k >> 5) * 4 + ((k >> 3) & 3);
    W1B[((size_t)(p * 256 + n)) * 8 + (k & 7)] = (bf16)W1[idx];
  } else {
    int i2 = idx - 192 * 256;
    int k = i2 / 192, n = i2 % 192;
    int p = (k >> 5) * 4 + ((k >> 3) & 3);
    W2B[((size_t)(p * 192 + n)) * 8 + (k & 7)] = (bf16)W2[i2];
  }
}

// ---------------- K1: encode + residual MLP (merged q+c, 256 thr) --------
// Blocks [0,8): queries (B-plane out). Blocks [8,2056): candidates
// (row-major out). Hidden in 2 halves of 128 cols; LDS 43 KB, 3 blocks/CU.
__global__ __launch_bounds__(256, 3) void k_encode(
    const float* __restrict__ xnq, const int* __restrict__ xcq,
    const float* __restrict__ xnc, const int* __restrict__ xcc,
    const float* __restrict__ Wn, const float* __restrict__ bn,
    const float* __restrict__ emb, const float* __restrict__ b1,
    const float* __restrict__ b2, const bf16* __restrict__ W1B,
    const bf16* __restrict__ W2B, bf16* __restrict__ ce,
    bf16* __restrict__ xeB, float* __restrict__ x2v,
    float* __restrict__ c2v) {
  __shared__ alignas(16) bf16 zt[64][200];    // encoded z / output (25.6 KB)
  __shared__ alignas(16) bf16 hth[64][136];   // hidden half (17.4 KB)
  __shared__ float n2l[64];

  const int t = threadIdx.x;
  const bool isq = blockIdx.x < 8;
  const int row0 = (isq ? blockIdx.x : blockIdx.x - 8) * 64;
  const float* __restrict__ xn = isq ? xnq : xnc;
  const int* __restrict__ xc = isq ? xcq : xcc;
  const int lane = t & 63, w = t >> 6;       // wave 0..3
  const int l15 = lane & 15, q = lane >> 4;

  if (t < 64) n2l[t] = 0.f;

  // ---- encode: wave w -> num features {2w,2w+1} + cat feature w ----
  {
    const int g = row0 + lane;
    float2 xv2 = *(const float2*)&xn[(size_t)g * 8 + 2 * w];
    int cv = xc[g * 4 + w];
#pragma unroll
    for (int f01 = 0; f01 < 2; f01++) {
      int f = 2 * w + f01;
      float xv = f01 ? xv2.y : xv2.x;
      f32x4 wv[4], bv[4];
#pragma unroll
      for (int i = 0; i < 4; i++) {
        wv[i] = *(const f32x4*)&Wn[f * 16 + i * 4];
        bv[i] = *(const f32x4*)&bn[f * 16 + i * 4];
      }
      bf16x8 p0, p1;
#pragma unroll
      for (int u = 0; u < 8; u++) {
        p0[u] = (bf16)(xv * wv[u >> 2][u & 3] + bv[u >> 2][u & 3]);
        p1[u] = (bf16)(xv * wv[2 + (u >> 2)][u & 3] + bv[2 + (u >> 2)][u & 3]);
      }
      *(bf16x8*)&zt[lane][f * 16] = p0;
      *(bf16x8*)&zt[lane][f * 16 + 8] = p1;
    }
    const float* er = &emb[(size_t)(w * 100 + cv) * 16];
    f32x4 e0 = *(const f32x4*)&er[0];
    f32x4 e1 = *(const f32x4*)&er[4];
    f32x4 e2 = *(const f32x4*)&er[8];
    f32x4 e3 = *(const f32x4*)&er[12];
    bf16x8 pc0, pc1;
#pragma unroll
    for (int u = 0; u < 4; u++) {
      pc0[u] = (bf16)e0[u]; pc0[4 + u] = (bf16)e1[u];
      pc1[u] = (bf16)e2[u]; pc1[4 + u] = (bf16)e3[u];
    }
    *(bf16x8*)&zt[lane][128 + w * 16] = pc0;
    *(bf16x8*)&zt[lane][128 + w * 16 + 8] = pc1;
  }
  __syncthreads();

  f32x4 z4 = {0.f, 0.f, 0.f, 0.f};
  f32x4 acc2[4][3];
#pragma unroll
  for (int mi = 0; mi < 4; mi++)
#pragma unroll
    for (int ni = 0; ni < 3; ni++) acc2[mi][ni] = z4;

#pragma unroll
  for (int h = 0; h < 2; ++h) {
    if (h) __syncthreads();        // prior G2 reads of hth done

    // ---- G1 half: wave w owns local cols [w*32, w*32+32) ----
    {
      f32x4 acc1[4][2];
#pragma unroll
      for (int mi = 0; mi < 4; mi++)
#pragma unroll
        for (int ni = 0; ni < 2; ni++) acc1[mi][ni] = z4;
#pragma unroll 2
      for (int kk = 0; kk < 192; kk += 32) {
        bf16x8 a[4], b[2];
#pragma unroll
        for (int mi = 0; mi < 4; mi++)
          a[mi] = *(const bf16x8*)&zt[mi * 16 + l15][kk + q * 8];
        const bf16* wp = &W1B[(size_t)(((kk >> 5) * 4 + q) * 256 + h * 128 + w * 32 + l15) * 8];
#pragma unroll
        for (int ni = 0; ni < 2; ni++)
          b[ni] = *(const bf16x8*)&wp[ni * 128];
#pragma unroll
        for (int mi = 0; mi < 4; mi++)
#pragma unroll
          for (int ni = 0; ni < 2; ni++)
            acc1[mi][ni] = __builtin_amdgcn_mfma_f32_16x16x32_bf16(a[mi], b[ni], acc1[mi][ni], 0, 0, 0);
      }
#pragma unroll
      for (int ni = 0; ni < 2; ni++) {
        int nl = w * 32 + ni * 16 + l15;
        float bb = b1[h * 128 + nl];
#pragma unroll
        for (int mi = 0; mi < 4; mi++)
#pragma unroll
          for (int r = 0; r < 4; r++) {
            float hv = acc1[mi][ni][r] + bb;
            hth[mi * 16 + q * 4 + r][nl] = (bf16)(hv > 0.f ? hv : 0.f);
          }
      }
    }
    __syncthreads();

    // ---- G2 partial: k in [h*128, h*128+128); wave w owns n [48w,48w+48) --
#pragma unroll 2
    for (int kk2 = 0; kk2 < 128; kk2 += 32) {
      bf16x8 a[4], b[3];
#pragma unroll
      for (int mi = 0; mi < 4; mi++)
        a[mi] = *(const bf16x8*)&hth[mi * 16 + l15][kk2 + q * 8];
      const bf16* wp = &W2B[(size_t)(((h * 4 + (kk2 >> 5)) * 4 + q) * 192 + w * 48 + l15) * 8];
#pragma unroll
      for (int ni = 0; ni < 3; ni++)
        b[ni] = *(const bf16x8*)&wp[ni * 128];
#pragma unroll
      for (int mi = 0; mi < 4; mi++)
#pragma unroll
        for (int ni = 0; ni < 3; ni++)
          acc2[mi][ni] = __builtin_amdgcn_mfma_f32_16x16x32_bf16(a[mi], b[ni], acc2[mi][ni], 0, 0, 0);
    }
  }

  // ---- epilogue: v = z + acc2 + b2, in-place in zt (wave-private cols) ----
  {
    float nrm[4][4];
#pragma unroll
    for (int mi = 0; mi < 4; mi++)
#pragma unroll
      for (int r = 0; r < 4; r++) nrm[mi][r] = 0.f;
#pragma unroll
    for (int ni = 0; ni < 3; ni++) {
      int n = w * 48 + ni * 16 + l15;
      float bb = b2[n];
#pragma unroll
      for (int mi = 0; mi < 4; mi++)
#pragma unroll
        for (int r = 0; r < 4; r++) {
          int rr = mi * 16 + q * 4 + r;
          float v = (float)zt[rr][n] + acc2[mi][ni][r] + bb;
          zt[rr][n] = (bf16)v;
          nrm[mi][r] += v * v;
        }
    }
#pragma unroll
    for (int mi = 0; mi < 4; mi++)
#pragma unroll
      for (int r = 0; r < 4; r++) {
        float s = nrm[mi][r];
        s += __shfl_xor(s, 1);
        s += __shfl_xor(s, 2);
        s += __shfl_xor(s, 4);
        s += __shfl_xor(s, 8);
        if (l15 == 0) atomicAdd(&n2l[mi * 16 + q * 4 + r], s);
      }
  }
  __syncthreads();

  // ---- copy-out ----
  if (isq) {
    // queries: B-plane layout xeB[(p*512 + row)*8 + j], p = col/8
    for (int cc = w; cc < 24; cc += 4) {
      bf16x8 v = *(const bf16x8*)&zt[lane][cc * 8];
      *(bf16x8*)&xeB[((size_t)cc * NQ + row0 + lane) * 8] = v;
    }
    if (t < 64) x2v[row0 + t] = n2l[t];
  } else {
    // candidates: row-major, fully coalesced 8B granules
    uint2* dst = (uint2*)(ce + (size_t)row0 * DIM);   // 48 uint2 per row
#pragma unroll
    for (int j = t; j < 64 * 48; j += 256) {
      int r = j / 48, cc = j - r * 48;
      dst[j] = *(const uint2*)&zt[r][cc * 4];
    }
    if (t < 64) c2v[row0 + t] = n2l[t];
  }
}

// ---------------- K3: dist + exp + PV — barrier-free flash ----------------
// Grid 1024 = 512 cand-slices x 2 query-halves (b, b+512 share ce slice AND
// XCD). Block = 256 cands x 256 q. NO ct staging: A-frags read directly
// from global ce (24.6 KB/chunk, L1-resident, shared by 4 waves + paired
// block). ET wave-private; only barriers are the final P-staging pair.
__global__ __launch_bounds__(256, 4) void k_dist(
    const bf16* __restrict__ xeB, const float* __restrict__ x2v,
    const bf16* __restrict__ ce, const float* __restrict__ c2v,
    const float* __restrict__ cy, float* __restrict__ P) {
  __shared__ alignas(16) char smem[12288];     // ET (9.2 KB) / P stage (12.3 KB)
  bf16 (*ET)[16][72] = (bf16(*)[16][72])smem;  // ET[w][qrow][cand]

  const int t = threadIdx.x;
  const int slice = blockIdx.x & (NSLICE - 1);
  const int half = blockIdx.x >> 9;
  const int n0 = slice * 256;
  const int qh = half * 256;
  const int lane = t & 63, w = t >> 6;
  const int l15 = lane & 15, q = lane >> 4;

  f32x4 z4 = {0.f, 0.f, 0.f, 0.f};
  f32x4 oacc[2][2];            // [qt][nq] — compile-time indexed only
#pragma unroll
  for (int qt = 0; qt < 2; qt++)
#pragma unroll
    for (int nq = 0; nq < 2; nq++) oacc[qt][nq] = z4;

  // query norms hoisted (compile-time indices -> registers)
  float x2a[2][2];
#pragma unroll
  for (int qt = 0; qt < 2; qt++)
#pragma unroll
    for (int nq = 0; nq < 2; nq++)
      x2a[qt][nq] = x2v[qh + qt * 128 + w * 32 + nq * 16 + l15];

#pragma unroll 1
  for (int c = 0; c < 4; ++c) {
    const bf16* __restrict__ cb = ce + (size_t)(n0 + c * 64) * DIM;
    const float* __restrict__ c2b = c2v + n0 + c * 64;

    // Y B-frags for this chunk (col 10 = ones -> l)
    bf16x8 yf[2];
#pragma unroll
    for (int kb = 0; kb < 2; kb++)
#pragma unroll
      for (int jj = 0; jj < 8; jj++) {
        int cand = n0 + c * 64 + kb * 32 + q * 8 + jj;
        float v = (l15 < 10) ? cy[(size_t)cand * NY + l15]
                             : (l15 == 10 ? 1.f : 0.f);
        yf[kb][jj] = (bf16)v;
      }

#pragma unroll
    for (int qt = 0; qt < 2; ++qt) {           // FULLY UNROLLED
      const int qbase = qh + qt * 128 + w * 32;
      f32x4 acc[4][2];         // [mc][nq]
#pragma unroll
      for (int mc = 0; mc < 4; mc++)
#pragma unroll
        for (int nq = 0; nq < 2; nq++) acc[mc][nq] = z4;

      // dist GEMM: A direct from global ce (L1-hot), B = xeB planes (L2-hot)
#pragma unroll 1
      for (int kk = 0; kk < 192; kk += 32) {
        bf16x8 a[4], b[2];
#pragma unroll
        for (int mc = 0; mc < 4; mc++)
          a[mc] = *(const bf16x8*)&cb[(size_t)(mc * 16 + l15) * DIM + kk + q * 8];
        const bf16* xp = &xeB[(size_t)(((kk >> 5) * 4 + q) * NQ + qbase + l15) * 8];
#pragma unroll
        for (int nq = 0; nq < 2; nq++)
          b[nq] = *(const bf16x8*)&xp[nq * 128];
#pragma unroll
        for (int mc = 0; mc < 4; mc++)
#pragma unroll
          for (int nq = 0; nq < 2; nq++)
            acc[mc][nq] = __builtin_amdgcn_mfma_f32_16x16x32_bf16(a[mc], b[nq], acc[mc][nq], 0, 0, 0);
      }

      // per 16-query group: exp -> ET (wave-private 16 rows) -> PV MFMA
#pragma unroll
      for (int nq = 0; nq < 2; ++nq) {
#pragma unroll
        for (int mc = 0; mc < 4; mc++) {
          f32x4 cc = *(const f32x4*)&c2b[mc * 16 + q * 4];
          bf16x4 ev;
#pragma unroll
          for (int r = 0; r < 4; r++) {
            float d2 = __builtin_fmaf(-2.f, acc[mc][nq][r], x2a[qt][nq] + cc[r]);
            ev[r] = (bf16)__expf(-sqrtf(__builtin_fabsf(d2)));
          }
          *(bf16x4*)&ET[w][l15][mc * 16 + q * 4] = ev;
        }
#pragma unroll
        for (int kb = 0; kb < 2; kb++) {
          bf16x8 a = *(const bf16x8*)&ET[w][l15][kb * 32 + q * 8];
          oacc[qt][nq] = __builtin_amdgcn_mfma_f32_16x16x32_bf16(a, yf[kb], oacc[qt][nq], 0, 0, 0);
        }
      }
    }
  }

  // ---- dense P write: stage in LDS (ET region dead), contiguous f32x4 ----
  __syncthreads();
  float* Pst = (float*)smem;                   // 256 q x 12 = 12.3 KB
  if (l15 < 11) {
#pragma unroll
    for (int qt = 0; qt < 2; qt++)
#pragma unroll
      for (int nq = 0; nq < 2; nq++)
#pragma unroll
        for (int r = 0; r < 4; r++) {
          int lq = qt * 128 + w * 32 + nq * 16 + q * 4 + r;
          Pst[lq * 12 + l15] = oacc[qt][nq][r];
        }
  }
  __syncthreads();
  {
    f32x4* Pg = (f32x4*)(P + (size_t)blockIdx.x * 3072);   // 256*12 floats
    const f32x4* Ps = (const f32x4*)Pst;
#pragma unroll
    for (int i = t; i < 768; i += 256) Pg[i] = Ps[i];
  }
}

// ---------------- K4: combine (pure sum — no max needed) ----------------
__global__ __launch_bounds__(512) void k_comb(const float* __restrict__ P,
                                              float* __restrict__ out) {
  __shared__ float red[8][11];
  const int t = threadIdx.x;
  const int qy = blockIdx.x;
  const int lane = t & 63, w = t >> 6;

  // record for (block = half*512 + slice, localq = qy&255); slice = t
  const float* p = &P[((size_t)((qy >> 8) * 512 + t) * 256 + (qy & 255)) * 12];
  f32x4 v0 = *(const f32x4*)&p[0];
  f32x4 v1 = *(const f32x4*)&p[4];
  f32x4 v2 = *(const f32x4*)&p[8];
  float s[11];
#pragma unroll
  for (int j = 0; j < 4; j++) s[j] = v0[j];
#pragma unroll
  for (int j = 0; j < 4; j++) s[4 + j] = v1[j];
#pragma unroll
  for (int j = 0; j < 3; j++) s[8 + j] = v2[j];
#pragma unroll
  for (int d = 1; d < 64; d <<= 1)
#pragma unroll
    for (int j = 0; j < 11; j++) s[j] += __shfl_xor(s[j], d);
  if (lane == 0)
#pragma unroll
    for (int j = 0; j < 11; j++) red[w][j] = s[j];
  __syncthreads();
  if (t < 10) {
    float o = 0.f, l = 0.f;
#pragma unroll
    for (int i = 0; i < 8; i++) { o += red[i][t]; l += red[i][10]; }
    out[qy * NY + t] = o / l;
  }
}

// ---------------- launcher ----------------
extern "C" void kernel_launch(void* const* d_in, const int* in_sizes, int n_in,
                              void* d_out, int out_size, void* d_ws, size_t ws_size,
                              hipStream_t stream) {
  (void)in_sizes; (void)n_in; (void)out_size; (void)ws_size;
  const float* x_num = (const float*)d_in[0];
  const int*   x_cat = (const int*)d_in[1];
  const float* c_num = (const float*)d_in[2];
  const int*   c_cat = (const int*)d_in[3];
  const float* c_y   = (const float*)d_in[4];
  const float* W_num = (const float*)d_in[5];
  const float* b_num = (const float*)d_in[6];
  const float* emb   = (const float*)d_in[7];
  const float* W1    = (const float*)d_in[8];
  const float* b1    = (const float*)d_in[9];
  const float* W2    = (const float*)d_in[10];
  const float* b2    = (const float*)d_in[11];
  float* out = (float*)d_out;

  char* ws = (char*)d_ws;
  bf16*  W1B = (bf16*)(ws + OFF_W1B);
  bf16*  W2B = (bf16*)(ws + OFF_W2B);
  bf16*  xeB = (bf16*)(ws + OFF_XEB);
  float* x2v = (float*)(ws + OFF_X2);
  bf16*  ce  = (bf16*)(ws + OFF_CE);
  float* c2v = (float*)(ws + OFF_C2);
  float* P   = (float*)(ws + OFF_P);

  k_prep<<<dim3(384), dim3(256), 0, stream>>>(W1, W2, W1B, W2B);
  k_encode<<<dim3(8 + NC / 64), dim3(256), 0, stream>>>(
      x_num, x_cat, c_num, c_cat, W_num, b_num, emb, b1, b2, W1B, W2B,
      ce, xeB, x2v, c2v);
  k_dist<<<dim3(2 * NSLICE), dim3(256), 0, stream>>>(xeB, x2v, ce, c2v, c_y, P);
  k_comb<<<dim3(NQ), dim3(512), 0, stream>>>(P, out);
}

// Round 10
// 221.878 us; speedup vs baseline: 1.1035x; 1.1035x over previous
//
#include <hip/hip_runtime.h>
#include <hip/hip_bf16.h>

// ModernNCA fused bf16-MFMA pipeline, v10.
// B=512 queries, N=131072 candidates, D=192, H=256, NY=10.
// v10 = v8's staged k_dist (direct-global A-reads of v9 reverted: 16-line
// gather per instr was latency death) + (1) register-prefetch of the next
// ce chunk issued AFTER the staging barrier so global latency overlaps
// compute, (2) Y pre-packed into B-fragment order (2 coalesced loads/chunk
// replace 16 divergent scalar gathers), (3) x2 hoisted to registers.
// Merged encode launch (v9) kept.
typedef __bf16 bf16;
typedef __attribute__((ext_vector_type(8))) __bf16 bf16x8;
typedef __attribute__((ext_vector_type(4))) __bf16 bf16x4;
typedef __attribute__((ext_vector_type(4))) float f32x4;

#define NQ     512
#define NC     131072
#define DIM    192
#define HID    256
#define NY     10
#define NSLICE 512           // cand slices of 256; k_dist grid = 2*NSLICE

// ---------------- workspace layout (bytes) ----------------
#define OFF_W1B 0u                              // 24 planes x 256 x 8 bf16 = 98304
#define OFF_W2B (OFF_W1B + 98304u)              // 32 planes x 192 x 8 bf16 = 98304
#define OFF_XEB (OFF_W2B + 98304u)              // 24 planes x 512 x 8 bf16 = 196608
#define OFF_X2  (OFF_XEB + 196608u)             // 512 f32 = 2048
#define OFF_CE  (OFF_X2 + 2048u)                // 131072x192 bf16 = 50331648
#define OFF_C2  (OFF_CE + 50331648u)            // 131072 f32 = 524288
#define OFF_P   (OFF_C2 + 524288u)              // 1024 x 256 x 12 f32 = 12582912
#define OFF_YB  (OFF_P + 12582912u)             // 4096 p32 x 64 lanes x 8 bf16 = 4194304
// total = 68,028,416 B  (< proven 76.4 MB envelope)

// ---------------- K0: weight cast + Y B-fragment pack ----------
// Blocks [0,384): weights. Plane p = (k>>5)*4 + ((k>>3)&3); elem j = k&7.
// Blocks [384,1408): YB[(p32*64 + lane)*8 + jj] = lane=(q*16+l15):
//   cand = p32*32 + q*8 + jj; val = l15<10 ? cy[cand*10+l15] : (l15==10).
__global__ __launch_bounds__(256) void k_prep(const float* __restrict__ W1,
                                              const float* __restrict__ W2,
                                              const float* __restrict__ cy,
                                              bf16* __restrict__ W1B,
                                              bf16* __restrict__ W2B,
                                              bf16* __restrict__ YB) {
  if (blockIdx.x < 384) {
    int idx = blockIdx.x * 256 + threadIdx.x;   // 0..98303
    if (idx < 192 * 256) {
      int k = idx / 256, n = idx % 256;
      int p = (k >> 5) * 4 + ((k >> 3) & 3);
      W1B[((size_t)(p * 256 + n)) * 8 + (k & 7)] = (bf16)W1[idx];
    } else {
      int i2 = idx - 192 * 256;
      int k = i2 / 192, n = i2 % 192;
      int p = (k >> 5) * 4 + ((k >> 3) & 3);
      W2B[((size_t)(p * 192 + n)) * 8 + (k & 7)] = (bf16)W2[i2];
    }
  } else {
    int u = (blockIdx.x - 384) * 256 + threadIdx.x;   // 0..262143
    int p32 = u >> 6, lane6 = u & 63;
    int qq = lane6 >> 4, l15 = lane6 & 15;
    bf16x8 v;
#pragma unroll
    for (int jj = 0; jj < 8; jj++) {
      int cand = p32 * 32 + qq * 8 + jj;
      float x = (l15 < 10) ? cy[(size_t)cand * NY + l15] : (l15 == 10 ? 1.f : 0.f);
      v[jj] = (bf16)x;
    }
    *(bf16x8*)&YB[(size_t)u * 8] = v;
  }
}

// ---------------- K1: encode + residual MLP (merged q+c, 256 thr) --------
// Blocks [0,8): queries (B-plane out). Blocks [8,2056): candidates
// (row-major out). Hidden in 2 halves of 128 cols; LDS 43 KB, 3 blocks/CU.
__global__ __launch_bounds__(256, 3) void k_encode(
    const float* __restrict__ xnq, const int* __restrict__ xcq,
    const float* __restrict__ xnc, const int* __restrict__ xcc,
    const float* __restrict__ Wn, const float* __restrict__ bn,
    const float* __restrict__ emb, const float* __restrict__ b1,
    const float* __restrict__ b2, const bf16* __restrict__ W1B,
    const bf16* __restrict__ W2B, bf16* __restrict__ ce,
    bf16* __restrict__ xeB, float* __restrict__ x2v,
    float* __restrict__ c2v) {
  __shared__ alignas(16) bf16 zt[64][200];    // encoded z / output (25.6 KB)
  __shared__ alignas(16) bf16 hth[64][136];   // hidden half (17.4 KB)
  __shared__ float n2l[64];

  const int t = threadIdx.x;
  const bool isq = blockIdx.x < 8;
  const int row0 = (isq ? blockIdx.x : blockIdx.x - 8) * 64;
  const float* __restrict__ xn = isq ? xnq : xnc;
  const int* __restrict__ xc = isq ? xcq : xcc;
  const int lane = t & 63, w = t >> 6;       // wave 0..3
  const int l15 = lane & 15, q = lane >> 4;

  if (t < 64) n2l[t] = 0.f;

  // ---- encode: wave w -> num features {2w,2w+1} + cat feature w ----
  {
    const int g = row0 + lane;
    float2 xv2 = *(const float2*)&xn[(size_t)g * 8 + 2 * w];
    int cv = xc[g * 4 + w];
#pragma unroll
    for (int f01 = 0; f01 < 2; f01++) {
      int f = 2 * w + f01;
      float xv = f01 ? xv2.y : xv2.x;
      f32x4 wv[4], bv[4];
#pragma unroll
      for (int i = 0; i < 4; i++) {
        wv[i] = *(const f32x4*)&Wn[f * 16 + i * 4];
        bv[i] = *(const f32x4*)&bn[f * 16 + i * 4];
      }
      bf16x8 p0, p1;
#pragma unroll
      for (int u = 0; u < 8; u++) {
        p0[u] = (bf16)(xv * wv[u >> 2][u & 3] + bv[u >> 2][u & 3]);
        p1[u] = (bf16)(xv * wv[2 + (u >> 2)][u & 3] + bv[2 + (u >> 2)][u & 3]);
      }
      *(bf16x8*)&zt[lane][f * 16] = p0;
      *(bf16x8*)&zt[lane][f * 16 + 8] = p1;
    }
    const float* er = &emb[(size_t)(w * 100 + cv) * 16];
    f32x4 e0 = *(const f32x4*)&er[0];
    f32x4 e1 = *(const f32x4*)&er[4];
    f32x4 e2 = *(const f32x4*)&er[8];
    f32x4 e3 = *(const f32x4*)&er[12];
    bf16x8 pc0, pc1;
#pragma unroll
    for (int u = 0; u < 4; u++) {
      pc0[u] = (bf16)e0[u]; pc0[4 + u] = (bf16)e1[u];
      pc1[u] = (bf16)e2[u]; pc1[4 + u] = (bf16)e3[u];
    }
    *(bf16x8*)&zt[lane][128 + w * 16] = pc0;
    *(bf16x8*)&zt[lane][128 + w * 16 + 8] = pc1;
  }
  __syncthreads();

  f32x4 z4 = {0.f, 0.f, 0.f, 0.f};
  f32x4 acc2[4][3];
#pragma unroll
  for (int mi = 0; mi < 4; mi++)
#pragma unroll
    for (int ni = 0; ni < 3; ni++) acc2[mi][ni] = z4;

#pragma unroll
  for (int h = 0; h < 2; ++h) {
    if (h) __syncthreads();        // prior G2 reads of hth done

    // ---- G1 half: wave w owns local cols [w*32, w*32+32) ----
    {
      f32x4 acc1[4][2];
#pragma unroll
      for (int mi = 0; mi < 4; mi++)
#pragma unroll
        for (int ni = 0; ni < 2; ni++) acc1[mi][ni] = z4;
#pragma unroll 2
      for (int kk = 0; kk < 192; kk += 32) {
        bf16x8 a[4], b[2];
#pragma unroll
        for (int mi = 0; mi < 4; mi++)
          a[mi] = *(const bf16x8*)&zt[mi * 16 + l15][kk + q * 8];
        const bf16* wp = &W1B[(size_t)(((kk >> 5) * 4 + q) * 256 + h * 128 + w * 32 + l15) * 8];
#pragma unroll
        for (int ni = 0; ni < 2; ni++)
          b[ni] = *(const bf16x8*)&wp[ni * 128];
#pragma unroll
        for (int mi = 0; mi < 4; mi++)
#pragma unroll
          for (int ni = 0; ni < 2; ni++)
            acc1[mi][ni] = __builtin_amdgcn_mfma_f32_16x16x32_bf16(a[mi], b[ni], acc1[mi][ni], 0, 0, 0);
      }
#pragma unroll
      for (int ni = 0; ni < 2; ni++) {
        int nl = w * 32 + ni * 16 + l15;
        float bb = b1[h * 128 + nl];
#pragma unroll
        for (int mi = 0; mi < 4; mi++)
#pragma unroll
          for (int r = 0; r < 4; r++) {
            float hv = acc1[mi][ni][r] + bb;
            hth[mi * 16 + q * 4 + r][nl] = (bf16)(hv > 0.f ? hv : 0.f);
          }
      }
    }
    __syncthreads();

    // ---- G2 partial: k in [h*128, h*128+128); wave w owns n [48w,48w+48) --
#pragma unroll 2
    for (int kk2 = 0; kk2 < 128; kk2 += 32) {
      bf16x8 a[4], b[3];
#pragma unroll
      for (int mi = 0; mi < 4; mi++)
        a[mi] = *(const bf16x8*)&hth[mi * 16 + l15][kk2 + q * 8];
      const bf16* wp = &W2B[(size_t)(((h * 4 + (kk2 >> 5)) * 4 + q) * 192 + w * 48 + l15) * 8];
#pragma unroll
      for (int ni = 0; ni < 3; ni++)
        b[ni] = *(const bf16x8*)&wp[ni * 128];
#pragma unroll
      for (int mi = 0; mi < 4; mi++)
#pragma unroll
        for (int ni = 0; ni < 3; ni++)
          acc2[mi][ni] = __builtin_amdgcn_mfma_f32_16x16x32_bf16(a[mi], b[ni], acc2[mi][ni], 0, 0, 0);
    }
  }

  // ---- epilogue: v = z + acc2 + b2, in-place in zt (wave-private cols) ----
  {
    float nrm[4][4];
#pragma unroll
    for (int mi = 0; mi < 4; mi++)
#pragma unroll
      for (int r = 0; r < 4; r++) nrm[mi][r] = 0.f;
#pragma unroll
    for (int ni = 0; ni < 3; ni++) {
      int n = w * 48 + ni * 16 + l15;
      float bb = b2[n];
#pragma unroll
      for (int mi = 0; mi < 4; mi++)
#pragma unroll
        for (int r = 0; r < 4; r++) {
          int rr = mi * 16 + q * 4 + r;
          float v = (float)zt[rr][n] + acc2[mi][ni][r] + bb;
          zt[rr][n] = (bf16)v;
          nrm[mi][r] += v * v;
        }
    }
#pragma unroll
    for (int mi = 0; mi < 4; mi++)
#pragma unroll
      for (int r = 0; r < 4; r++) {
        float s = nrm[mi][r];
        s += __shfl_xor(s, 1);
        s += __shfl_xor(s, 2);
        s += __shfl_xor(s, 4);
        s += __shfl_xor(s, 8);
        if (l15 == 0) atomicAdd(&n2l[mi * 16 + q * 4 + r], s);
      }
  }
  __syncthreads();

  // ---- copy-out ----
  if (isq) {
    // queries: B-plane layout xeB[(p*512 + row)*8 + j], p = col/8
    for (int cc = w; cc < 24; cc += 4) {
      bf16x8 v = *(const bf16x8*)&zt[lane][cc * 8];
      *(bf16x8*)&xeB[((size_t)cc * NQ + row0 + lane) * 8] = v;
    }
    if (t < 64) x2v[row0 + t] = n2l[t];
  } else {
    // candidates: row-major, fully coalesced 8B granules
    uint2* dst = (uint2*)(ce + (size_t)row0 * DIM);   // 48 uint2 per row
#pragma unroll
    for (int j = t; j < 64 * 48; j += 256) {
      int r = j / 48, cc = j - r * 48;
      dst[j] = *(const uint2*)&zt[r][cc * 4];
    }
    if (t < 64) c2v[row0 + t] = n2l[t];
  }
}

// ---------------- K3: dist + exp + PV, staged + prefetched ----------------
// Grid 1024 = 512 cand-slices x 2 query-halves (b, b+512 share ce slice AND
// XCD). Block = 256 cands x 256 q; 4 chunks of 64 staged in LDS. Next
// chunk's ce lines prefetched into VGPRs AFTER the staging barrier so the
// global latency overlaps compute (the barrier drain only sees ds_writes).
__global__ __launch_bounds__(256, 4) void k_dist(
    const bf16* __restrict__ xeB, const float* __restrict__ x2v,
    const bf16* __restrict__ ce, const float* __restrict__ c2v,
    const bf16* __restrict__ YB, float* __restrict__ P) {
  __shared__ alignas(16) bf16 ct[64][200];     // chunk staging (25.6 KB); P stage after
  __shared__ alignas(16) bf16 ET[4][16][72];   // per-wave exp tiles (9.2 KB)

  const int t = threadIdx.x;
  const int slice = blockIdx.x & (NSLICE - 1);
  const int half = blockIdx.x >> 9;
  const int n0 = slice * 256;
  const int qh = half * 256;
  const int lane = t & 63, w = t >> 6;
  const int l15 = lane & 15, q = lane >> 4;
  const int sr = t >> 2, squ = t & 3;          // staging role: row, quarter

  f32x4 z4 = {0.f, 0.f, 0.f, 0.f};
  f32x4 oacc[2][2];            // [qt][nq] — compile-time indexed only
#pragma unroll
  for (int qt = 0; qt < 2; qt++)
#pragma unroll
    for (int nq = 0; nq < 2; nq++) oacc[qt][nq] = z4;

  // query norms hoisted once (compile-time indices -> registers)
  float x2a[2][2];
#pragma unroll
  for (int qt = 0; qt < 2; qt++)
#pragma unroll
    for (int nq = 0; nq < 2; nq++)
      x2a[qt][nq] = x2v[qh + qt * 128 + w * 32 + nq * 16 + l15];

  // prologue: prefetch chunk 0 into registers
  uint4 pre[6];
  {
    const uint4* src = (const uint4*)(ce + (size_t)(n0 + sr) * DIM);
#pragma unroll
    for (int i = 0; i < 6; i++) pre[i] = src[squ * 6 + i];
  }

#pragma unroll 1
  for (int c = 0; c < 4; ++c) {
    if (c) __syncthreads();                    // prior compute's ct reads done
    {
      uint4* dst = (uint4*)&ct[sr][0];
#pragma unroll
      for (int i = 0; i < 6; i++) dst[squ * 6 + i] = pre[i];
    }
    __syncthreads();

    // prefetch next chunk NOW — latency covered by this chunk's compute
    if (c < 3) {
      const uint4* src = (const uint4*)(ce + (size_t)(n0 + (c + 1) * 64 + sr) * DIM);
#pragma unroll
      for (int i = 0; i < 6; i++) pre[i] = src[squ * 6 + i];
    }

    // Y B-frags: pre-packed, lane-contiguous (1 KB/wave per load)
    bf16x8 yf[2];
#pragma unroll
    for (int kb = 0; kb < 2; kb++)
      yf[kb] = *(const bf16x8*)&YB[((size_t)((n0 >> 5) + c * 2 + kb) * 64 + lane) * 8];
    // candidate norms: broadcast f32x4 loads (L1-hot)
    f32x4 c2r[4];
#pragma unroll
    for (int mc = 0; mc < 4; mc++)
      c2r[mc] = *(const f32x4*)&c2v[n0 + c * 64 + mc * 16 + q * 4];

#pragma unroll
    for (int qt = 0; qt < 2; ++qt) {           // FULLY UNROLLED
      const int qbase = qh + qt * 128 + w * 32;
      f32x4 acc[4][2];         // [mc][nq]
#pragma unroll
      for (int mc = 0; mc < 4; mc++)
#pragma unroll
        for (int nq = 0; nq < 2; nq++) acc[mc][nq] = z4;

      // dist GEMM: A = ct (LDS), B = xeB planes (global, L2-hot)
#pragma unroll 1
      for (int kk = 0; kk < 192; kk += 32) {
        bf16x8 a[4], b[2];
#pragma unroll
        for (int mc = 0; mc < 4; mc++)
          a[mc] = *(const bf16x8*)&ct[mc * 16 + l15][kk + q * 8];
        const bf16* xp = &xeB[(size_t)(((kk >> 5) * 4 + q) * NQ + qbase + l15) * 8];
#pragma unroll
        for (int nq = 0; nq < 2; nq++)
          b[nq] = *(const bf16x8*)&xp[nq * 128];
#pragma unroll
        for (int mc = 0; mc < 4; mc++)
#pragma unroll
          for (int nq = 0; nq < 2; nq++)
            acc[mc][nq] = __builtin_amdgcn_mfma_f32_16x16x32_bf16(a[mc], b[nq], acc[mc][nq], 0, 0, 0);
      }

      // per 16-query group: exp -> ET (wave-private 16 rows) -> PV MFMA
#pragma unroll
      for (int nq = 0; nq < 2; ++nq) {
#pragma unroll
        for (int mc = 0; mc < 4; mc++) {
          bf16x4 ev;
#pragma unroll
          for (int r = 0; r < 4; r++) {
            float d2 = __builtin_fmaf(-2.f, acc[mc][nq][r], x2a[qt][nq] + c2r[mc][r]);
            ev[r] = (bf16)__expf(-sqrtf(__builtin_fabsf(d2)));
          }
          *(bf16x4*)&ET[w][l15][mc * 16 + q * 4] = ev;
        }
#pragma unroll
        for (int kb = 0; kb < 2; kb++) {
          bf16x8 a = *(const bf16x8*)&ET[w][l15][kb * 32 + q * 8];
          oacc[qt][nq] = __builtin_amdgcn_mfma_f32_16x16x32_bf16(a, yf[kb], oacc[qt][nq], 0, 0, 0);
        }
      }
    }
  }

  // ---- dense P write: stage in LDS (ct is dead), contiguous f32x4 ----
  __syncthreads();
  float* Pst = (float*)&ct[0][0];              // 256 q x 12 = 12.3 KB
  if (l15 < 11) {
#pragma unroll
    for (int qt = 0; qt < 2; qt++)
#pragma unroll
      for (int nq = 0; nq < 2; nq++)
#pragma unroll
        for (int r = 0; r < 4; r++) {
          int lq = qt * 128 + w * 32 + nq * 16 + q * 4 + r;
          Pst[lq * 12 + l15] = oacc[qt][nq][r];
        }
  }
  __syncthreads();
  {
    f32x4* Pg = (f32x4*)(P + (size_t)blockIdx.x * 3072);   // 256*12 floats
    const f32x4* Ps = (const f32x4*)Pst;
#pragma unroll
    for (int i = t; i < 768; i += 256) Pg[i] = Ps[i];
  }
}

// ---------------- K4: combine (pure sum — no max needed) ----------------
__global__ __launch_bounds__(512) void k_comb(const float* __restrict__ P,
                                              float* __restrict__ out) {
  __shared__ float red[8][11];
  const int t = threadIdx.x;
  const int qy = blockIdx.x;
  const int lane = t & 63, w = t >> 6;

  // record for (block = half*512 + slice, localq = qy&255); slice = t
  const float* p = &P[((size_t)((qy >> 8) * 512 + t) * 256 + (qy & 255)) * 12];
  f32x4 v0 = *(const f32x4*)&p[0];
  f32x4 v1 = *(const f32x4*)&p[4];
  f32x4 v2 = *(const f32x4*)&p[8];
  float s[11];
#pragma unroll
  for (int j = 0; j < 4; j++) s[j] = v0[j];
#pragma unroll
  for (int j = 0; j < 4; j++) s[4 + j] = v1[j];
#pragma unroll
  for (int j = 0; j < 3; j++) s[8 + j] = v2[j];
#pragma unroll
  for (int d = 1; d < 64; d <<= 1)
#pragma unroll
    for (int j = 0; j < 11; j++) s[j] += __shfl_xor(s[j], d);
  if (lane == 0)
#pragma unroll
    for (int j = 0; j < 11; j++) red[w][j] = s[j];
  __syncthreads();
  if (t < 10) {
    float o = 0.f, l = 0.f;
#pragma unroll
    for (int i = 0; i < 8; i++) { o += red[i][t]; l += red[i][10]; }
    out[qy * NY + t] = o / l;
  }
}

// ---------------- launcher ----------------
extern "C" void kernel_launch(void* const* d_in, const int* in_sizes, int n_in,
                              void* d_out, int out_size, void* d_ws, size_t ws_size,
                              hipStream_t stream) {
  (void)in_sizes; (void)n_in; (void)out_size; (void)ws_size;
  const float* x_num = (const float*)d_in[0];
  const int*   x_cat = (const int*)d_in[1];
  const float* c_num = (const float*)d_in[2];
  const int*   c_cat = (const int*)d_in[3];
  const float* c_y   = (const float*)d_in[4];
  const float* W_num = (const float*)d_in[5];
  const float* b_num = (const float*)d_in[6];
  const float* emb   = (const float*)d_in[7];
  const float* W1    = (const float*)d_in[8];
  const float* b1    = (const float*)d_in[9];
  const float* W2    = (const float*)d_in[10];
  const float* b2    = (const float*)d_in[11];
  float* out = (float*)d_out;

  char* ws = (char*)d_ws;
  bf16*  W1B = (bf16*)(ws + OFF_W1B);
  bf16*  W2B = (bf16*)(ws + OFF_W2B);
  bf16*  xeB = (bf16*)(ws + OFF_XEB);
  float* x2v = (float*)(ws + OFF_X2);
  bf16*  ce  = (bf16*)(ws + OFF_CE);
  float* c2v = (float*)(ws + OFF_C2);
  float* P   = (float*)(ws + OFF_P);
  bf16*  YB  = (bf16*)(ws + OFF_YB);

  k_prep<<<dim3(1408), dim3(256), 0, stream>>>(W1, W2, c_y, W1B, W2B, YB);
  k_encode<<<dim3(8 + NC / 64), dim3(256), 0, stream>>>(
      x_num, x_cat, c_num, c_cat, W_num, b_num, emb, b1, b2, W1B, W2B,
      ce, xeB, x2v, c2v);
  k_dist<<<dim3(2 * NSLICE), dim3(256), 0, stream>>>(xeB, x2v, ce, c2v, YB, P);
  k_comb<<<dim3(NQ), dim3(512), 0, stream>>>(P, out);
}

// Round 11
// 198.749 us; speedup vs baseline: 1.2319x; 1.1164x over previous
//
#include <hip/hip_runtime.h>
#include <hip/hip_bf16.h>

// ModernNCA fused bf16-MFMA pipeline, v11.
// B=512 queries, N=131072 candidates, D=192, H=256, NY=10.
// v11: k_dist = v8 staging (no reg-carried prefetch — v10's pre[] spilled
// under the VGPR cap) + qt loop ELIMINATED: wave owns 64 queries, one
// K-pass per chunk with acc[4][4] (halves A-LDS reads + loop overhead per
// MFMA). (256,3) so ~160 regs fit without spill. YB prepack + merged
// encode kept. All register arrays compile-time indexed (the #1 lesson).
typedef __bf16 bf16;
typedef __attribute__((ext_vector_type(8))) __bf16 bf16x8;
typedef __attribute__((ext_vector_type(4))) __bf16 bf16x4;
typedef __attribute__((ext_vector_type(4))) float f32x4;

#define NQ     512
#define NC     131072
#define DIM    192
#define HID    256
#define NY     10
#define NSLICE 512           // cand slices of 256; k_dist grid = 2*NSLICE

// ---------------- workspace layout (bytes) ----------------
#define OFF_W1B 0u                              // 24 planes x 256 x 8 bf16 = 98304
#define OFF_W2B (OFF_W1B + 98304u)              // 32 planes x 192 x 8 bf16 = 98304
#define OFF_XEB (OFF_W2B + 98304u)              // 24 planes x 512 x 8 bf16 = 196608
#define OFF_X2  (OFF_XEB + 196608u)             // 512 f32 = 2048
#define OFF_CE  (OFF_X2 + 2048u)                // 131072x192 bf16 = 50331648
#define OFF_C2  (OFF_CE + 50331648u)            // 131072 f32 = 524288
#define OFF_P   (OFF_C2 + 524288u)              // 1024 x 256 x 12 f32 = 12582912
#define OFF_YB  (OFF_P + 12582912u)             // 4096 p32 x 64 lanes x 8 bf16 = 4194304

// ---------------- K0: weight cast + Y B-fragment pack ----------
__global__ __launch_bounds__(256) void k_prep(const float* __restrict__ W1,
                                              const float* __restrict__ W2,
                                              const float* __restrict__ cy,
                                              bf16* __restrict__ W1B,
                                              bf16* __restrict__ W2B,
                                              bf16* __restrict__ YB) {
  if (blockIdx.x < 384) {
    int idx = blockIdx.x * 256 + threadIdx.x;   // 0..98303
    if (idx < 192 * 256) {
      int k = idx / 256, n = idx % 256;
      int p = (k >> 5) * 4 + ((k >> 3) & 3);
      W1B[((size_t)(p * 256 + n)) * 8 + (k & 7)] = (bf16)W1[idx];
    } else {
      int i2 = idx - 192 * 256;
      int k = i2 / 192, n = i2 % 192;
      int p = (k >> 5) * 4 + ((k >> 3) & 3);
      W2B[((size_t)(p * 192 + n)) * 8 + (k & 7)] = (bf16)W2[i2];
    }
  } else {
    int u = (blockIdx.x - 384) * 256 + threadIdx.x;   // 0..262143
    int p32 = u >> 6, lane6 = u & 63;
    int qq = lane6 >> 4, l15 = lane6 & 15;
    bf16x8 v;
#pragma unroll
    for (int jj = 0; jj < 8; jj++) {
      int cand = p32 * 32 + qq * 8 + jj;
      float x = (l15 < 10) ? cy[(size_t)cand * NY + l15] : (l15 == 10 ? 1.f : 0.f);
      v[jj] = (bf16)x;
    }
    *(bf16x8*)&YB[(size_t)u * 8] = v;
  }
}

// ---------------- K1: encode + residual MLP (merged q+c, 256 thr) --------
__global__ __launch_bounds__(256, 3) void k_encode(
    const float* __restrict__ xnq, const int* __restrict__ xcq,
    const float* __restrict__ xnc, const int* __restrict__ xcc,
    const float* __restrict__ Wn, const float* __restrict__ bn,
    const float* __restrict__ emb, const float* __restrict__ b1,
    const float* __restrict__ b2, const bf16* __restrict__ W1B,
    const bf16* __restrict__ W2B, bf16* __restrict__ ce,
    bf16* __restrict__ xeB, float* __restrict__ x2v,
    float* __restrict__ c2v) {
  __shared__ alignas(16) bf16 zt[64][200];    // encoded z / output (25.6 KB)
  __shared__ alignas(16) bf16 hth[64][136];   // hidden half (17.4 KB)
  __shared__ float n2l[64];

  const int t = threadIdx.x;
  const bool isq = blockIdx.x < 8;
  const int row0 = (isq ? blockIdx.x : blockIdx.x - 8) * 64;
  const float* __restrict__ xn = isq ? xnq : xnc;
  const int* __restrict__ xc = isq ? xcq : xcc;
  const int lane = t & 63, w = t >> 6;       // wave 0..3
  const int l15 = lane & 15, q = lane >> 4;

  if (t < 64) n2l[t] = 0.f;

  // ---- encode: wave w -> num features {2w,2w+1} + cat feature w ----
  {
    const int g = row0 + lane;
    float2 xv2 = *(const float2*)&xn[(size_t)g * 8 + 2 * w];
    int cv = xc[g * 4 + w];
#pragma unroll
    for (int f01 = 0; f01 < 2; f01++) {
      int f = 2 * w + f01;
      float xv = f01 ? xv2.y : xv2.x;
      f32x4 wv[4], bv[4];
#pragma unroll
      for (int i = 0; i < 4; i++) {
        wv[i] = *(const f32x4*)&Wn[f * 16 + i * 4];
        bv[i] = *(const f32x4*)&bn[f * 16 + i * 4];
      }
      bf16x8 p0, p1;
#pragma unroll
      for (int u = 0; u < 8; u++) {
        p0[u] = (bf16)(xv * wv[u >> 2][u & 3] + bv[u >> 2][u & 3]);
        p1[u] = (bf16)(xv * wv[2 + (u >> 2)][u & 3] + bv[2 + (u >> 2)][u & 3]);
      }
      *(bf16x8*)&zt[lane][f * 16] = p0;
      *(bf16x8*)&zt[lane][f * 16 + 8] = p1;
    }
    const float* er = &emb[(size_t)(w * 100 + cv) * 16];
    f32x4 e0 = *(const f32x4*)&er[0];
    f32x4 e1 = *(const f32x4*)&er[4];
    f32x4 e2 = *(const f32x4*)&er[8];
    f32x4 e3 = *(const f32x4*)&er[12];
    bf16x8 pc0, pc1;
#pragma unroll
    for (int u = 0; u < 4; u++) {
      pc0[u] = (bf16)e0[u]; pc0[4 + u] = (bf16)e1[u];
      pc1[u] = (bf16)e2[u]; pc1[4 + u] = (bf16)e3[u];
    }
    *(bf16x8*)&zt[lane][128 + w * 16] = pc0;
    *(bf16x8*)&zt[lane][128 + w * 16 + 8] = pc1;
  }
  __syncthreads();

  f32x4 z4 = {0.f, 0.f, 0.f, 0.f};
  f32x4 acc2[4][3];
#pragma unroll
  for (int mi = 0; mi < 4; mi++)
#pragma unroll
    for (int ni = 0; ni < 3; ni++) acc2[mi][ni] = z4;

#pragma unroll
  for (int h = 0; h < 2; ++h) {
    if (h) __syncthreads();        // prior G2 reads of hth done

    // ---- G1 half: wave w owns local cols [w*32, w*32+32) ----
    {
      f32x4 acc1[4][2];
#pragma unroll
      for (int mi = 0; mi < 4; mi++)
#pragma unroll
        for (int ni = 0; ni < 2; ni++) acc1[mi][ni] = z4;
#pragma unroll 2
      for (int kk = 0; kk < 192; kk += 32) {
        bf16x8 a[4], b[2];
#pragma unroll
        for (int mi = 0; mi < 4; mi++)
          a[mi] = *(const bf16x8*)&zt[mi * 16 + l15][kk + q * 8];
        const bf16* wp = &W1B[(size_t)(((kk >> 5) * 4 + q) * 256 + h * 128 + w * 32 + l15) * 8];
#pragma unroll
        for (int ni = 0; ni < 2; ni++)
          b[ni] = *(const bf16x8*)&wp[ni * 128];
#pragma unroll
        for (int mi = 0; mi < 4; mi++)
#pragma unroll
          for (int ni = 0; ni < 2; ni++)
            acc1[mi][ni] = __builtin_amdgcn_mfma_f32_16x16x32_bf16(a[mi], b[ni], acc1[mi][ni], 0, 0, 0);
      }
#pragma unroll
      for (int ni = 0; ni < 2; ni++) {
        int nl = w * 32 + ni * 16 + l15;
        float bb = b1[h * 128 + nl];
#pragma unroll
        for (int mi = 0; mi < 4; mi++)
#pragma unroll
          for (int r = 0; r < 4; r++) {
            float hv = acc1[mi][ni][r] + bb;
            hth[mi * 16 + q * 4 + r][nl] = (bf16)(hv > 0.f ? hv : 0.f);
          }
      }
    }
    __syncthreads();

    // ---- G2 partial: k in [h*128, h*128+128); wave w owns n [48w,48w+48) --
#pragma unroll 2
    for (int kk2 = 0; kk2 < 128; kk2 += 32) {
      bf16x8 a[4], b[3];
#pragma unroll
      for (int mi = 0; mi < 4; mi++)
        a[mi] = *(const bf16x8*)&hth[mi * 16 + l15][kk2 + q * 8];
      const bf16* wp = &W2B[(size_t)(((h * 4 + (kk2 >> 5)) * 4 + q) * 192 + w * 48 + l15) * 8];
#pragma unroll
      for (int ni = 0; ni < 3; ni++)
        b[ni] = *(const bf16x8*)&wp[ni * 128];
#pragma unroll
      for (int mi = 0; mi < 4; mi++)
#pragma unroll
        for (int ni = 0; ni < 3; ni++)
          acc2[mi][ni] = __builtin_amdgcn_mfma_f32_16x16x32_bf16(a[mi], b[ni], acc2[mi][ni], 0, 0, 0);
    }
  }

  // ---- epilogue: v = z + acc2 + b2, in-place in zt (wave-private cols) ----
  {
    float nrm[4][4];
#pragma unroll
    for (int mi = 0; mi < 4; mi++)
#pragma unroll
      for (int r = 0; r < 4; r++) nrm[mi][r] = 0.f;
#pragma unroll
    for (int ni = 0; ni < 3; ni++) {
      int n = w * 48 + ni * 16 + l15;
      float bb = b2[n];
#pragma unroll
      for (int mi = 0; mi < 4; mi++)
#pragma unroll
        for (int r = 0; r < 4; r++) {
          int rr = mi * 16 + q * 4 + r;
          float v = (float)zt[rr][n] + acc2[mi][ni][r] + bb;
          zt[rr][n] = (bf16)v;
          nrm[mi][r] += v * v;
        }
    }
#pragma unroll
    for (int mi = 0; mi < 4; mi++)
#pragma unroll
      for (int r = 0; r < 4; r++) {
        float s = nrm[mi][r];
        s += __shfl_xor(s, 1);
        s += __shfl_xor(s, 2);
        s += __shfl_xor(s, 4);
        s += __shfl_xor(s, 8);
        if (l15 == 0) atomicAdd(&n2l[mi * 16 + q * 4 + r], s);
      }
  }
  __syncthreads();

  // ---- copy-out ----
  if (isq) {
    for (int cc = w; cc < 24; cc += 4) {
      bf16x8 v = *(const bf16x8*)&zt[lane][cc * 8];
      *(bf16x8*)&xeB[((size_t)cc * NQ + row0 + lane) * 8] = v;
    }
    if (t < 64) x2v[row0 + t] = n2l[t];
  } else {
    uint2* dst = (uint2*)(ce + (size_t)row0 * DIM);   // 48 uint2 per row
#pragma unroll
    for (int j = t; j < 64 * 48; j += 256) {
      int r = j / 48, cc = j - r * 48;
      dst[j] = *(const uint2*)&zt[r][cc * 4];
    }
    if (t < 64) c2v[row0 + t] = n2l[t];
  }
}

// ---------------- K3: dist + exp + PV, single K-pass per chunk ----------
// Grid 1024 = 512 cand-slices x 2 query-halves (b, b+512 share ce slice
// AND XCD). Block = 256 cands x 256 q; wave owns 64 queries (NO qt loop).
// 4 chunks of 64 cands staged in LDS (v8 staging, no register carry).
__global__ __launch_bounds__(256, 3) void k_dist(
    const bf16* __restrict__ xeB, const float* __restrict__ x2v,
    const bf16* __restrict__ ce, const float* __restrict__ c2v,
    const bf16* __restrict__ YB, float* __restrict__ P) {
  __shared__ alignas(16) bf16 ct[64][200];     // chunk staging (25.6 KB); P stage after
  __shared__ alignas(16) bf16 ET[4][16][72];   // per-wave exp tiles (9.2 KB)

  const int t = threadIdx.x;
  const int slice = blockIdx.x & (NSLICE - 1);
  const int half = blockIdx.x >> 9;
  const int n0 = slice * 256;
  const int qh = half * 256;
  const int lane = t & 63, w = t >> 6;
  const int l15 = lane & 15, q = lane >> 4;
  const int qbase = qh + w * 64;               // wave's 64 queries, fixed

  f32x4 z4 = {0.f, 0.f, 0.f, 0.f};
  f32x4 oacc[4];               // [nq] — compile-time indexed only
#pragma unroll
  for (int nq = 0; nq < 4; nq++) oacc[nq] = z4;

  // query norms hoisted once
  float x2a[4];
#pragma unroll
  for (int nq = 0; nq < 4; nq++) x2a[nq] = x2v[qbase + nq * 16 + l15];

#pragma unroll 1
  for (int c = 0; c < 4; ++c) {
    if (c) __syncthreads();                    // prior compute's ct reads done
    {
      int sr = t >> 2, squ = t & 3;
      const uint4* src = (const uint4*)(ce + (size_t)(n0 + c * 64 + sr) * DIM);
      uint4* dst = (uint4*)&ct[sr][0];
#pragma unroll
      for (int i = 0; i < 6; i++) dst[squ * 6 + i] = src[squ * 6 + i];
    }
    __syncthreads();

    // Y B-frags: pre-packed, lane-contiguous
    bf16x8 yf[2];
#pragma unroll
    for (int kb = 0; kb < 2; kb++)
      yf[kb] = *(const bf16x8*)&YB[((size_t)((n0 >> 5) + c * 2 + kb) * 64 + lane) * 8];
    // candidate norms: broadcast f32x4 loads (L1-hot)
    f32x4 c2r[4];
#pragma unroll
    for (int mc = 0; mc < 4; mc++)
      c2r[mc] = *(const f32x4*)&c2v[n0 + c * 64 + mc * 16 + q * 4];

    // single dist-GEMM pass: 64 cands x 64 queries
    f32x4 acc[4][4];           // [mc][nq]
#pragma unroll
    for (int mc = 0; mc < 4; mc++)
#pragma unroll
      for (int nq = 0; nq < 4; nq++) acc[mc][nq] = z4;

#pragma unroll 1
    for (int kk = 0; kk < 192; kk += 32) {
      bf16x8 a[4], b[4];
#pragma unroll
      for (int mc = 0; mc < 4; mc++)
        a[mc] = *(const bf16x8*)&ct[mc * 16 + l15][kk + q * 8];
      const bf16* xp = &xeB[(size_t)(((kk >> 5) * 4 + q) * NQ + qbase + l15) * 8];
#pragma unroll
      for (int nq = 0; nq < 4; nq++)
        b[nq] = *(const bf16x8*)&xp[nq * 128];
#pragma unroll
      for (int mc = 0; mc < 4; mc++)
#pragma unroll
        for (int nq = 0; nq < 4; nq++)
          acc[mc][nq] = __builtin_amdgcn_mfma_f32_16x16x32_bf16(a[mc], b[nq], acc[mc][nq], 0, 0, 0);
    }

    // per 16-query group: exp -> ET (wave-private 16 rows) -> PV MFMA
#pragma unroll
    for (int nq = 0; nq < 4; ++nq) {
#pragma unroll
      for (int mc = 0; mc < 4; mc++) {
        bf16x4 ev;
#pragma unroll
        for (int r = 0; r < 4; r++) {
          float d2 = __builtin_fmaf(-2.f, acc[mc][nq][r], x2a[nq] + c2r[mc][r]);
          ev[r] = (bf16)__expf(-sqrtf(__builtin_fabsf(d2)));
        }
        *(bf16x4*)&ET[w][l15][mc * 16 + q * 4] = ev;
      }
#pragma unroll
      for (int kb = 0; kb < 2; kb++) {
        bf16x8 a = *(const bf16x8*)&ET[w][l15][kb * 32 + q * 8];
        oacc[nq] = __builtin_amdgcn_mfma_f32_16x16x32_bf16(a, yf[kb], oacc[nq], 0, 0, 0);
      }
    }
  }

  // ---- dense P write: stage in LDS (ct is dead), contiguous f32x4 ----
  __syncthreads();
  float* Pst = (float*)&ct[0][0];              // 256 q x 12 = 12.3 KB
  if (l15 < 11) {
#pragma unroll
    for (int nq = 0; nq < 4; nq++)
#pragma unroll
      for (int r = 0; r < 4; r++) {
        int lq = w * 64 + nq * 16 + q * 4 + r;
        Pst[lq * 12 + l15] = oacc[nq][r];
      }
  }
  __syncthreads();
  {
    f32x4* Pg = (f32x4*)(P + (size_t)blockIdx.x * 3072);   // 256*12 floats
    const f32x4* Ps = (const f32x4*)Pst;
#pragma unroll
    for (int i = t; i < 768; i += 256) Pg[i] = Ps[i];
  }
}

// ---------------- K4: combine (pure sum — no max needed) ----------------
__global__ __launch_bounds__(512) void k_comb(const float* __restrict__ P,
                                              float* __restrict__ out) {
  __shared__ float red[8][11];
  const int t = threadIdx.x;
  const int qy = blockIdx.x;
  const int lane = t & 63, w = t >> 6;

  // record for (block = half*512 + slice, localq = qy&255); slice = t
  const float* p = &P[((size_t)((qy >> 8) * 512 + t) * 256 + (qy & 255)) * 12];
  f32x4 v0 = *(const f32x4*)&p[0];
  f32x4 v1 = *(const f32x4*)&p[4];
  f32x4 v2 = *(const f32x4*)&p[8];
  float s[11];
#pragma unroll
  for (int j = 0; j < 4; j++) s[j] = v0[j];
#pragma unroll
  for (int j = 0; j < 4; j++) s[4 + j] = v1[j];
#pragma unroll
  for (int j = 0; j < 3; j++) s[8 + j] = v2[j];
#pragma unroll
  for (int d = 1; d < 64; d <<= 1)
#pragma unroll
    for (int j = 0; j < 11; j++) s[j] += __shfl_xor(s[j], d);
  if (lane == 0)
#pragma unroll
    for (int j = 0; j < 11; j++) red[w][j] = s[j];
  __syncthreads();
  if (t < 10) {
    float o = 0.f, l = 0.f;
#pragma unroll
    for (int i = 0; i < 8; i++) { o += red[i][t]; l += red[i][10]; }
    out[qy * NY + t] = o / l;
  }
}

// ---------------- launcher ----------------
extern "C" void kernel_launch(void* const* d_in, const int* in_sizes, int n_in,
                              void* d_out, int out_size, void* d_ws, size_t ws_size,
                              hipStream_t stream) {
  (void)in_sizes; (void)n_in; (void)out_size; (void)ws_size;
  const float* x_num = (const float*)d_in[0];
  const int*   x_cat = (const int*)d_in[1];
  const float* c_num = (const float*)d_in[2];
  const int*   c_cat = (const int*)d_in[3];
  const float* c_y   = (const float*)d_in[4];
  const float* W_num = (const float*)d_in[5];
  const float* b_num = (const float*)d_in[6];
  const float* emb   = (const float*)d_in[7];
  const float* W1    = (const float*)d_in[8];
  const float* b1    = (const float*)d_in[9];
  const float* W2    = (const float*)d_in[10];
  const float* b2    = (const float*)d_in[11];
  float* out = (float*)d_out;

  char* ws = (char*)d_ws;
  bf16*  W1B = (bf16*)(ws + OFF_W1B);
  bf16*  W2B = (bf16*)(ws + OFF_W2B);
  bf16*  xeB = (bf16*)(ws + OFF_XEB);
  float* x2v = (float*)(ws + OFF_X2);
  bf16*  ce  = (bf16*)(ws + OFF_CE);
  float* c2v = (float*)(ws + OFF_C2);
  float* P   = (float*)(ws + OFF_P);
  bf16*  YB  = (bf16*)(ws + OFF_YB);

  k_prep<<<dim3(1408), dim3(256), 0, stream>>>(W1, W2, c_y, W1B, W2B, YB);
  k_encode<<<dim3(8 + NC / 64), dim3(256), 0, stream>>>(
      x_num, x_cat, c_num, c_cat, W_num, b_num, emb, b1, b2, W1B, W2B,
      ce, xeB, x2v, c2v);
  k_dist<<<dim3(2 * NSLICE), dim3(256), 0, stream>>>(xeB, x2v, ce, c2v, YB, P);
  k_comb<<<dim3(NQ), dim3(512), 0, stream>>>(P, out);
}

// Round 12
// 177.853 us; speedup vs baseline: 1.3766x; 1.1175x over previous
//
#include <hip/hip_runtime.h>
#include <hip/hip_bf16.h>

// ModernNCA fused pipeline, v12.
// B=512 queries, N=131072 candidates, D=192, H=256, NY=10.
// v12: distance GEMM in FP8 e4m3 (OCP) — same MFMA rate as bf16 but half
// the bytes everywhere in k_dist (ce 25 MB, b64 LDS A-reads, half staging).
// Norms computed FROM the fp8-rounded vectors (dist exact in fp32 given
// rounded inputs) and pre-scaled by K=(log2 e)^2 so the epilogue is
// exp2(-sqrt(|fma(-2K,s,n)|)) — one fewer VALU op/elem. Encode GEMMs stay
// bf16. All register arrays compile-time indexed (the #1 session lesson).
typedef __bf16 bf16;
typedef __attribute__((ext_vector_type(8))) __bf16 bf16x8;
typedef __attribute__((ext_vector_type(4))) __bf16 bf16x4;
typedef __attribute__((ext_vector_type(4))) float f32x4;

#define NQ     512
#define NC     131072
#define DIM    192
#define HID    256
#define NY     10
#define NSLICE 512           // cand slices of 256; k_dist grid = 2*NSLICE

#define KL2E   2.0813689810056077f    // (log2 e)^2
#define N2KL2E -4.1627379620112154f   // -2*(log2 e)^2

// ---------------- workspace layout (bytes) ----------------
#define OFF_W1B 0u                              // 98304
#define OFF_W2B (OFF_W1B + 98304u)              // 98304
#define OFF_XE8 (OFF_W2B + 98304u)              // 24 planes x 512 x 8 B fp8 = 98304
#define OFF_X2  (OFF_XE8 + 98304u)              // 512 f32 = 2048
#define OFF_CE8 (OFF_X2 + 2048u)                // 131072x192 fp8 = 25165824
#define OFF_C2  (OFF_CE8 + 25165824u)           // 131072 f32 = 524288
#define OFF_P   (OFF_C2 + 524288u)              // 1024 x 256 x 12 f32 = 12582912
#define OFF_YB  (OFF_P + 12582912u)             // 4194304

// ---------------- K0: weight cast + Y B-fragment pack ----------
__global__ __launch_bounds__(256) void k_prep(const float* __restrict__ W1,
                                              const float* __restrict__ W2,
                                              const float* __restrict__ cy,
                                              bf16* __restrict__ W1B,
                                              bf16* __restrict__ W2B,
                                              bf16* __restrict__ YB) {
  if (blockIdx.x < 384) {
    int idx = blockIdx.x * 256 + threadIdx.x;   // 0..98303
    if (idx < 192 * 256) {
      int k = idx / 256, n = idx % 256;
      int p = (k >> 5) * 4 + ((k >> 3) & 3);
      W1B[((size_t)(p * 256 + n)) * 8 + (k & 7)] = (bf16)W1[idx];
    } else {
      int i2 = idx - 192 * 256;
      int k = i2 / 192, n = i2 % 192;
      int p = (k >> 5) * 4 + ((k >> 3) & 3);
      W2B[((size_t)(p * 192 + n)) * 8 + (k & 7)] = (bf16)W2[i2];
    }
  } else {
    int u = (blockIdx.x - 384) * 256 + threadIdx.x;   // 0..262143
    int p32 = u >> 6, lane6 = u & 63;
    int qq = lane6 >> 4, l15 = lane6 & 15;
    bf16x8 v;
#pragma unroll
    for (int jj = 0; jj < 8; jj++) {
      int cand = p32 * 32 + qq * 8 + jj;
      float x = (l15 < 10) ? cy[(size_t)cand * NY + l15] : (l15 == 10 ? 1.f : 0.f);
      v[jj] = (bf16)x;
    }
    *(bf16x8*)&YB[(size_t)u * 8] = v;
  }
}

// ---------------- K1: encode + residual MLP (merged q+c, 256 thr) --------
// bf16 GEMMs; output encodings quantized to fp8 e4m3, norms computed from
// the ROUNDED values and pre-scaled by KL2E.
__global__ __launch_bounds__(256, 3) void k_encode(
    const float* __restrict__ xnq, const int* __restrict__ xcq,
    const float* __restrict__ xnc, const int* __restrict__ xcc,
    const float* __restrict__ Wn, const float* __restrict__ bn,
    const float* __restrict__ emb, const float* __restrict__ b1,
    const float* __restrict__ b2, const bf16* __restrict__ W1B,
    const bf16* __restrict__ W2B, unsigned char* __restrict__ ce8,
    unsigned char* __restrict__ xe8, float* __restrict__ x2v,
    float* __restrict__ c2v) {
  __shared__ alignas(16) bf16 zt[64][200];    // encoded z (25.6 KB)
  __shared__ alignas(16) bf16 hth[64][136];   // hidden half (17.4 KB); reused as zs
  __shared__ float n2l[64];
  unsigned char* zs = (unsigned char*)&hth[0][0];   // fp8 out stage, stride 208

  const int t = threadIdx.x;
  const bool isq = blockIdx.x < 8;
  const int row0 = (isq ? blockIdx.x : blockIdx.x - 8) * 64;
  const float* __restrict__ xn = isq ? xnq : xnc;
  const int* __restrict__ xc = isq ? xcq : xcc;
  const int lane = t & 63, w = t >> 6;       // wave 0..3
  const int l15 = lane & 15, q = lane >> 4;

  if (t < 64) n2l[t] = 0.f;

  // ---- encode: wave w -> num features {2w,2w+1} + cat feature w ----
  {
    const int g = row0 + lane;
    float2 xv2 = *(const float2*)&xn[(size_t)g * 8 + 2 * w];
    int cv = xc[g * 4 + w];
#pragma unroll
    for (int f01 = 0; f01 < 2; f01++) {
      int f = 2 * w + f01;
      float xv = f01 ? xv2.y : xv2.x;
      f32x4 wv[4], bv[4];
#pragma unroll
      for (int i = 0; i < 4; i++) {
        wv[i] = *(const f32x4*)&Wn[f * 16 + i * 4];
        bv[i] = *(const f32x4*)&bn[f * 16 + i * 4];
      }
      bf16x8 p0, p1;
#pragma unroll
      for (int u = 0; u < 8; u++) {
        p0[u] = (bf16)(xv * wv[u >> 2][u & 3] + bv[u >> 2][u & 3]);
        p1[u] = (bf16)(xv * wv[2 + (u >> 2)][u & 3] + bv[2 + (u >> 2)][u & 3]);
      }
      *(bf16x8*)&zt[lane][f * 16] = p0;
      *(bf16x8*)&zt[lane][f * 16 + 8] = p1;
    }
    const float* er = &emb[(size_t)(w * 100 + cv) * 16];
    f32x4 e0 = *(const f32x4*)&er[0];
    f32x4 e1 = *(const f32x4*)&er[4];
    f32x4 e2 = *(const f32x4*)&er[8];
    f32x4 e3 = *(const f32x4*)&er[12];
    bf16x8 pc0, pc1;
#pragma unroll
    for (int u = 0; u < 4; u++) {
      pc0[u] = (bf16)e0[u]; pc0[4 + u] = (bf16)e1[u];
      pc1[u] = (bf16)e2[u]; pc1[4 + u] = (bf16)e3[u];
    }
    *(bf16x8*)&zt[lane][128 + w * 16] = pc0;
    *(bf16x8*)&zt[lane][128 + w * 16 + 8] = pc1;
  }
  __syncthreads();

  f32x4 z4 = {0.f, 0.f, 0.f, 0.f};
  f32x4 acc2[4][3];
#pragma unroll
  for (int mi = 0; mi < 4; mi++)
#pragma unroll
    for (int ni = 0; ni < 3; ni++) acc2[mi][ni] = z4;

#pragma unroll
  for (int h = 0; h < 2; ++h) {
    if (h) __syncthreads();        // prior G2 reads of hth done

    // ---- G1 half: wave w owns local cols [w*32, w*32+32) ----
    {
      f32x4 acc1[4][2];
#pragma unroll
      for (int mi = 0; mi < 4; mi++)
#pragma unroll
        for (int ni = 0; ni < 2; ni++) acc1[mi][ni] = z4;
#pragma unroll 2
      for (int kk = 0; kk < 192; kk += 32) {
        bf16x8 a[4], b[2];
#pragma unroll
        for (int mi = 0; mi < 4; mi++)
          a[mi] = *(const bf16x8*)&zt[mi * 16 + l15][kk + q * 8];
        const bf16* wp = &W1B[(size_t)(((kk >> 5) * 4 + q) * 256 + h * 128 + w * 32 + l15) * 8];
#pragma unroll
        for (int ni = 0; ni < 2; ni++)
          b[ni] = *(const bf16x8*)&wp[ni * 128];
#pragma unroll
        for (int mi = 0; mi < 4; mi++)
#pragma unroll
          for (int ni = 0; ni < 2; ni++)
            acc1[mi][ni] = __builtin_amdgcn_mfma_f32_16x16x32_bf16(a[mi], b[ni], acc1[mi][ni], 0, 0, 0);
      }
#pragma unroll
      for (int ni = 0; ni < 2; ni++) {
        int nl = w * 32 + ni * 16 + l15;
        float bb = b1[h * 128 + nl];
#pragma unroll
        for (int mi = 0; mi < 4; mi++)
#pragma unroll
          for (int r = 0; r < 4; r++) {
            float hv = acc1[mi][ni][r] + bb;
            hth[mi * 16 + q * 4 + r][nl] = (bf16)(hv > 0.f ? hv : 0.f);
          }
      }
    }
    __syncthreads();

    // ---- G2 partial: k in [h*128, h*128+128); wave w owns n [48w,48w+48) --
#pragma unroll 2
    for (int kk2 = 0; kk2 < 128; kk2 += 32) {
      bf16x8 a[4], b[3];
#pragma unroll
      for (int mi = 0; mi < 4; mi++)
        a[mi] = *(const bf16x8*)&hth[mi * 16 + l15][kk2 + q * 8];
      const bf16* wp = &W2B[(size_t)(((h * 4 + (kk2 >> 5)) * 4 + q) * 192 + w * 48 + l15) * 8];
#pragma unroll
      for (int ni = 0; ni < 3; ni++)
        b[ni] = *(const bf16x8*)&wp[ni * 128];
#pragma unroll
      for (int mi = 0; mi < 4; mi++)
#pragma unroll
        for (int ni = 0; ni < 3; ni++)
          acc2[mi][ni] = __builtin_amdgcn_mfma_f32_16x16x32_bf16(a[mi], b[ni], acc2[mi][ni], 0, 0, 0);
    }
  }
  __syncthreads();   // all hth reads done; safe to reuse as zs

  // ---- epilogue: v = z + acc2 + b2 -> fp8 (zs, stride 208), norms of
  // the ROUNDED values, pre-scaled by KL2E ----
  {
    float nrm[4][4];
#pragma unroll
    for (int mi = 0; mi < 4; mi++)
#pragma unroll
      for (int r = 0; r < 4; r++) nrm[mi][r] = 0.f;
#pragma unroll
    for (int ni = 0; ni < 3; ni++) {
      int n = w * 48 + ni * 16 + l15;
      float bb = b2[n];
#pragma unroll
      for (int mi = 0; mi < 4; mi++)
#pragma unroll
        for (int r = 0; r < 4; r++) {
          int rr = mi * 16 + q * 4 + r;
          float v = (float)zt[rr][n] + acc2[mi][ni][r] + bb;
          int pk = __builtin_amdgcn_cvt_pk_fp8_f32(v, v, 0, false);
          zs[rr * 208 + n] = (unsigned char)(pk & 0xff);
          float vr = __builtin_amdgcn_cvt_f32_fp8(pk, 0);
          nrm[mi][r] += vr * vr;
        }
    }
#pragma unroll
    for (int mi = 0; mi < 4; mi++)
#pragma unroll
      for (int r = 0; r < 4; r++) {
        float s = nrm[mi][r];
        s += __shfl_xor(s, 1);
        s += __shfl_xor(s, 2);
        s += __shfl_xor(s, 4);
        s += __shfl_xor(s, 8);
        if (l15 == 0) atomicAdd(&n2l[mi * 16 + q * 4 + r], s);
      }
  }
  __syncthreads();

  // ---- copy-out (fp8) ----
  if (isq) {
    // queries: B-plane layout xe8[(p*512 + row)*8 + j]
    for (int cc = w; cc < 24; cc += 4) {
      long v = *(const long*)&zs[lane * 208 + cc * 8];
      *(long*)&xe8[((size_t)cc * NQ + row0 + lane) * 8] = v;
    }
    if (t < 64) x2v[row0 + t] = n2l[t] * KL2E;
  } else {
    // candidates: row-major 192 B rows, coalesced uint copies
    unsigned int* dst = (unsigned int*)(ce8 + (size_t)row0 * DIM);
#pragma unroll
    for (int i = 0; i < 12; i++) {
      int j = t + 256 * i;                   // 0..3071 words
      int r = j / 48, cb = (j - r * 48) * 4;
      dst[j] = *(const unsigned int*)&zs[r * 208 + cb];
    }
    if (t < 64) c2v[row0 + t] = n2l[t] * KL2E;
  }
}

// ---------------- K3: fp8 dist + exp2 + bf16 PV ----------------
// Grid 1024 = 512 cand-slices x 2 query-halves (b, b+512 share ce slice
// AND XCD). Block = 256 cands x 256 q; wave owns 64 queries; 4 chunks of
// 64 cands staged in LDS as fp8 (3 uint4/thread).
__global__ __launch_bounds__(256, 3) void k_dist(
    const unsigned char* __restrict__ xe8, const float* __restrict__ x2v,
    const unsigned char* __restrict__ ce8, const float* __restrict__ c2v,
    const bf16* __restrict__ YB, float* __restrict__ P) {
  __shared__ alignas(16) unsigned char ct8[64][208];  // 13.3 KB; P stage after
  __shared__ alignas(16) bf16 ET[4][16][72];          // per-wave exp tiles (9.2 KB)

  const int t = threadIdx.x;
  const int slice = blockIdx.x & (NSLICE - 1);
  const int half = blockIdx.x >> 9;
  const int n0 = slice * 256;
  const int qh = half * 256;
  const int lane = t & 63, w = t >> 6;
  const int l15 = lane & 15, q = lane >> 4;
  const int qbase = qh + w * 64;               // wave's 64 queries, fixed

  f32x4 z4 = {0.f, 0.f, 0.f, 0.f};
  f32x4 oacc[4];               // [nq] — compile-time indexed only
#pragma unroll
  for (int nq = 0; nq < 4; nq++) oacc[nq] = z4;

  // query norms (pre-scaled by KL2E) hoisted once
  float x2a[4];
#pragma unroll
  for (int nq = 0; nq < 4; nq++) x2a[nq] = x2v[qbase + nq * 16 + l15];

#pragma unroll 1
  for (int c = 0; c < 4; ++c) {
    if (c) __syncthreads();                    // prior compute's ct8 reads done
    {
      int sr = t >> 2, squ = t & 3;
      const uint4* src = (const uint4*)(ce8 + (size_t)(n0 + c * 64 + sr) * DIM + squ * 48);
      uint4* dst = (uint4*)&ct8[sr][squ * 48];
#pragma unroll
      for (int i = 0; i < 3; i++) dst[i] = src[i];
    }
    __syncthreads();

    // Y B-frags: pre-packed bf16, lane-contiguous
    bf16x8 yf[2];
#pragma unroll
    for (int kb = 0; kb < 2; kb++)
      yf[kb] = *(const bf16x8*)&YB[((size_t)((slice * 8) + c * 2 + kb) * 64 + lane) * 8];
    // candidate norms (pre-scaled): broadcast f32x4 loads
    f32x4 c2r[4];
#pragma unroll
    for (int mc = 0; mc < 4; mc++)
      c2r[mc] = *(const f32x4*)&c2v[n0 + c * 64 + mc * 16 + q * 4];

    // single fp8 dist-GEMM pass: 64 cands x 64 queries
    f32x4 acc[4][4];           // [mc][nq]
#pragma unroll
    for (int mc = 0; mc < 4; mc++)
#pragma unroll
      for (int nq = 0; nq < 4; nq++) acc[mc][nq] = z4;

#pragma unroll 1
    for (int kk = 0; kk < 192; kk += 32) {
      long a[4], b[4];
#pragma unroll
      for (int mc = 0; mc < 4; mc++)
        a[mc] = *(const long*)&ct8[mc * 16 + l15][kk + q * 8];
      const unsigned char* xp = &xe8[(size_t)(((kk >> 5) * 4 + q) * NQ + qbase + l15) * 8];
#pragma unroll
      for (int nq = 0; nq < 4; nq++)
        b[nq] = *(const long*)&xp[nq * 128];
#pragma unroll
      for (int mc = 0; mc < 4; mc++)
#pragma unroll
        for (int nq = 0; nq < 4; nq++)
          acc[mc][nq] = __builtin_amdgcn_mfma_f32_16x16x32_fp8_fp8(a[mc], b[nq], acc[mc][nq], 0, 0, 0);
    }

    // epilogue: e = exp2(-sqrt(|K*d2|)) = exp(-dist); ET -> PV MFMA
#pragma unroll
    for (int nq = 0; nq < 4; ++nq) {
#pragma unroll
      for (int mc = 0; mc < 4; mc++) {
        bf16x4 ev;
#pragma unroll
        for (int r = 0; r < 4; r++) {
          float d2 = __builtin_fmaf(N2KL2E, acc[mc][nq][r], x2a[nq] + c2r[mc][r]);
          ev[r] = (bf16)__builtin_amdgcn_exp2f(-__builtin_amdgcn_sqrtf(__builtin_fabsf(d2)));
        }
        *(bf16x4*)&ET[w][l15][mc * 16 + q * 4] = ev;
      }
#pragma unroll
      for (int kb = 0; kb < 2; kb++) {
        bf16x8 a = *(const bf16x8*)&ET[w][l15][kb * 32 + q * 8];
        oacc[nq] = __builtin_amdgcn_mfma_f32_16x16x32_bf16(a, yf[kb], oacc[nq], 0, 0, 0);
      }
    }
  }

  // ---- dense P write: stage in LDS (ct8 is dead), contiguous f32x4 ----
  __syncthreads();
  float* Pst = (float*)&ct8[0][0];             // 256 q x 12 = 12.3 KB
  if (l15 < 11) {
#pragma unroll
    for (int nq = 0; nq < 4; nq++)
#pragma unroll
      for (int r = 0; r < 4; r++) {
        int lq = w * 64 + nq * 16 + q * 4 + r;
        Pst[lq * 12 + l15] = oacc[nq][r];
      }
  }
  __syncthreads();
  {
    f32x4* Pg = (f32x4*)(P + (size_t)blockIdx.x * 3072);   // 256*12 floats
    const f32x4* Ps = (const f32x4*)Pst;
#pragma unroll
    for (int i = t; i < 768; i += 256) Pg[i] = Ps[i];
  }
}

// ---------------- K4: combine (pure sum — no max needed) ----------------
__global__ __launch_bounds__(512) void k_comb(const float* __restrict__ P,
                                              float* __restrict__ out) {
  __shared__ float red[8][11];
  const int t = threadIdx.x;
  const int qy = blockIdx.x;
  const int lane = t & 63, w = t >> 6;

  // record for (block = half*512 + slice, localq = qy&255); slice = t
  const float* p = &P[((size_t)((qy >> 8) * 512 + t) * 256 + (qy & 255)) * 12];
  f32x4 v0 = *(const f32x4*)&p[0];
  f32x4 v1 = *(const f32x4*)&p[4];
  f32x4 v2 = *(const f32x4*)&p[8];
  float s[11];
#pragma unroll
  for (int j = 0; j < 4; j++) s[j] = v0[j];
#pragma unroll
  for (int j = 0; j < 4; j++) s[4 + j] = v1[j];
#pragma unroll
  for (int j = 0; j < 3; j++) s[8 + j] = v2[j];
#pragma unroll
  for (int d = 1; d < 64; d <<= 1)
#pragma unroll
    for (int j = 0; j < 11; j++) s[j] += __shfl_xor(s[j], d);
  if (lane == 0)
#pragma unroll
    for (int j = 0; j < 11; j++) red[w][j] = s[j];
  __syncthreads();
  if (t < 10) {
    float o = 0.f, l = 0.f;
#pragma unroll
    for (int i = 0; i < 8; i++) { o += red[i][t]; l += red[i][10]; }
    out[qy * NY + t] = o / l;
  }
}

// ---------------- launcher ----------------
extern "C" void kernel_launch(void* const* d_in, const int* in_sizes, int n_in,
                              void* d_out, int out_size, void* d_ws, size_t ws_size,
                              hipStream_t stream) {
  (void)in_sizes; (void)n_in; (void)out_size; (void)ws_size;
  const float* x_num = (const float*)d_in[0];
  const int*   x_cat = (const int*)d_in[1];
  const float* c_num = (const float*)d_in[2];
  const int*   c_cat = (const int*)d_in[3];
  const float* c_y   = (const float*)d_in[4];
  const float* W_num = (const float*)d_in[5];
  const float* b_num = (const float*)d_in[6];
  const float* emb   = (const float*)d_in[7];
  const float* W1    = (const float*)d_in[8];
  const float* b1    = (const float*)d_in[9];
  const float* W2    = (const float*)d_in[10];
  const float* b2    = (const float*)d_in[11];
  float* out = (float*)d_out;

  char* ws = (char*)d_ws;
  bf16*  W1B = (bf16*)(ws + OFF_W1B);
  bf16*  W2B = (bf16*)(ws + OFF_W2B);
  unsigned char* xe8 = (unsigned char*)(ws + OFF_XE8);
  float* x2v = (float*)(ws + OFF_X2);
  unsigned char* ce8 = (unsigned char*)(ws + OFF_CE8);
  float* c2v = (float*)(ws + OFF_C2);
  float* P   = (float*)(ws + OFF_P);
  bf16*  YB  = (bf16*)(ws + OFF_YB);

  k_prep<<<dim3(1408), dim3(256), 0, stream>>>(W1, W2, c_y, W1B, W2B, YB);
  k_encode<<<dim3(8 + NC / 64), dim3(256), 0, stream>>>(
      x_num, x_cat, c_num, c_cat, W_num, b_num, emb, b1, b2, W1B, W2B,
      ce8, xe8, x2v, c2v);
  k_dist<<<dim3(2 * NSLICE), dim3(256), 0, stream>>>(xe8, x2v, ce8, c2v, YB, P);
  k_comb<<<dim3(NQ), dim3(512), 0, stream>>>(P, out);
}

// Round 13
// 166.429 us; speedup vs baseline: 1.4711x; 1.0686x over previous
//
#include <hip/hip_runtime.h>
#include <hip/hip_bf16.h>

// ModernNCA fused pipeline, v13.
// B=512 queries, N=131072 candidates, D=192, H=256, NY=10.
// v13: encode MLP ported to fp8 e4m3 (z, hidden, W1, W2) — halves every
// byte in k_encode, full 256-col hidden fits in one LDS buffer so the
// 2-half structure collapses to 3 barriers, LDS 43.5->30.4 KB = 5
// blocks/CU. Epilogue quantizes in-place into zt8. k_dist (fp8, v12)
// unchanged. All register arrays compile-time indexed (#1 session lesson).
typedef __bf16 bf16;
typedef __attribute__((ext_vector_type(8))) __bf16 bf16x8;
typedef __attribute__((ext_vector_type(4))) __bf16 bf16x4;
typedef __attribute__((ext_vector_type(4))) float f32x4;

#define NQ     512
#define NC     131072
#define DIM    192
#define HID    256
#define NY     10
#define NSLICE 512           // cand slices of 256; k_dist grid = 2*NSLICE

#define KL2E   2.0813689810056077f    // (log2 e)^2
#define N2KL2E -4.1627379620112154f   // -2*(log2 e)^2

// ---------------- workspace layout (bytes) ----------------
#define OFF_W1B 0u                              // 24 planes x 256 x 8 B fp8 = 49152
#define OFF_W2B (OFF_W1B + 49152u)              // 32 planes x 192 x 8 B fp8 = 49152
#define OFF_XE8 (OFF_W2B + 49152u)              // 24 planes x 512 x 8 B fp8 = 98304
#define OFF_X2  (OFF_XE8 + 98304u)              // 512 f32 = 2048
#define OFF_CE8 (OFF_X2 + 2048u)                // 131072x192 fp8 = 25165824
#define OFF_C2  (OFF_CE8 + 25165824u)           // 131072 f32 = 524288
#define OFF_P   (OFF_C2 + 524288u)              // 1024 x 256 x 12 f32 = 12582912
#define OFF_YB  (OFF_P + 12582912u)             // 4194304

static __device__ __forceinline__ unsigned pk4(float a, float b, float c, float d) {
  unsigned w = __builtin_amdgcn_cvt_pk_fp8_f32(a, b, 0, false);
  w = __builtin_amdgcn_cvt_pk_fp8_f32(c, d, w, true);
  return w;
}

// ---------------- K0: fp8 weight planes + Y B-fragment pack ----------
__global__ __launch_bounds__(256) void k_prep(const float* __restrict__ W1,
                                              const float* __restrict__ W2,
                                              const float* __restrict__ cy,
                                              unsigned char* __restrict__ W1B8,
                                              unsigned char* __restrict__ W2B8,
                                              bf16* __restrict__ YB) {
  if (blockIdx.x < 384) {
    int idx = blockIdx.x * 256 + threadIdx.x;   // 0..98303
    if (idx < 192 * 256) {
      int k = idx / 256, n = idx % 256;
      int p = (k >> 5) * 4 + ((k >> 3) & 3);
      int pk = __builtin_amdgcn_cvt_pk_fp8_f32(W1[idx], W1[idx], 0, false);
      W1B8[((size_t)(p * 256 + n)) * 8 + (k & 7)] = (unsigned char)(pk & 0xff);
    } else {
      int i2 = idx - 192 * 256;
      int k = i2 / 192, n = i2 % 192;
      int p = (k >> 5) * 4 + ((k >> 3) & 3);
      int pk = __builtin_amdgcn_cvt_pk_fp8_f32(W2[i2], W2[i2], 0, false);
      W2B8[((size_t)(p * 192 + n)) * 8 + (k & 7)] = (unsigned char)(pk & 0xff);
    }
  } else {
    int u = (blockIdx.x - 384) * 256 + threadIdx.x;   // 0..262143
    int p32 = u >> 6, lane6 = u & 63;
    int qq = lane6 >> 4, l15 = lane6 & 15;
    bf16x8 v;
#pragma unroll
    for (int jj = 0; jj < 8; jj++) {
      int cand = p32 * 32 + qq * 8 + jj;
      float x = (l15 < 10) ? cy[(size_t)cand * NY + l15] : (l15 == 10 ? 1.f : 0.f);
      v[jj] = (bf16)x;
    }
    *(bf16x8*)&YB[(size_t)u * 8] = v;
  }
}

// ---------------- K1: fp8 encode + residual MLP (merged q+c, 256 thr) ----
// 3 barriers: encode -> G1(full H) -> G2+epilogue(in-place zt8) -> copyout.
// zt8 stride 208 (2-way b64 alias = free), hth8 stride 264 (conflict-free).
__global__ __launch_bounds__(256, 4) void k_encode(
    const float* __restrict__ xnq, const int* __restrict__ xcq,
    const float* __restrict__ xnc, const int* __restrict__ xcc,
    const float* __restrict__ Wn, const float* __restrict__ bn,
    const float* __restrict__ emb, const float* __restrict__ b1,
    const float* __restrict__ b2, const unsigned char* __restrict__ W1B8,
    const unsigned char* __restrict__ W2B8, unsigned char* __restrict__ ce8,
    unsigned char* __restrict__ xe8, float* __restrict__ x2v,
    float* __restrict__ c2v) {
  __shared__ alignas(16) unsigned char zt8[64][208];    // fp8 z / output (13.3 KB)
  __shared__ alignas(16) unsigned char hth8[64][264];   // fp8 hidden, full 256 (16.9 KB)
  __shared__ float n2l[64];

  const int t = threadIdx.x;
  const bool isq = blockIdx.x < 8;
  const int row0 = (isq ? blockIdx.x : blockIdx.x - 8) * 64;
  const float* __restrict__ xn = isq ? xnq : xnc;
  const int* __restrict__ xc = isq ? xcq : xcc;
  const int lane = t & 63, w = t >> 6;       // wave 0..3
  const int l15 = lane & 15, q = lane >> 4;

  if (t < 64) n2l[t] = 0.f;

  // ---- encode: wave w -> num features {2w,2w+1} + cat feature w (fp8) ----
  {
    const int g = row0 + lane;
    float2 xv2 = *(const float2*)&xn[(size_t)g * 8 + 2 * w];
    int cv = xc[g * 4 + w];
#pragma unroll
    for (int f01 = 0; f01 < 2; f01++) {
      int f = 2 * w + f01;
      float xv = f01 ? xv2.y : xv2.x;
      float zz[16];
#pragma unroll
      for (int i = 0; i < 4; i++) {
        f32x4 wv = *(const f32x4*)&Wn[f * 16 + i * 4];
        f32x4 bv = *(const f32x4*)&bn[f * 16 + i * 4];
#pragma unroll
        for (int u = 0; u < 4; u++) zz[i * 4 + u] = xv * wv[u] + bv[u];
      }
      uint4 pk;
      pk.x = pk4(zz[0], zz[1], zz[2], zz[3]);
      pk.y = pk4(zz[4], zz[5], zz[6], zz[7]);
      pk.z = pk4(zz[8], zz[9], zz[10], zz[11]);
      pk.w = pk4(zz[12], zz[13], zz[14], zz[15]);
      *(uint4*)&zt8[lane][f * 16] = pk;
    }
    const float* er = &emb[(size_t)(w * 100 + cv) * 16];
    f32x4 e0 = *(const f32x4*)&er[0];
    f32x4 e1 = *(const f32x4*)&er[4];
    f32x4 e2 = *(const f32x4*)&er[8];
    f32x4 e3 = *(const f32x4*)&er[12];
    uint4 pk;
    pk.x = pk4(e0[0], e0[1], e0[2], e0[3]);
    pk.y = pk4(e1[0], e1[1], e1[2], e1[3]);
    pk.z = pk4(e2[0], e2[1], e2[2], e2[3]);
    pk.w = pk4(e3[0], e3[1], e3[2], e3[3]);
    *(uint4*)&zt8[lane][128 + w * 16] = pk;
  }
  __syncthreads();

  f32x4 z4 = {0.f, 0.f, 0.f, 0.f};

  // ---- G1 (fp8): H = relu(Z @ W1 + b1); wave w owns cols [64w, 64w+64) ----
  {
    f32x4 acc1[4][4];          // [mi][ni]
#pragma unroll
    for (int mi = 0; mi < 4; mi++)
#pragma unroll
      for (int ni = 0; ni < 4; ni++) acc1[mi][ni] = z4;
#pragma unroll 2
    for (int kk = 0; kk < 192; kk += 32) {
      long a[4], b[4];
#pragma unroll
      for (int mi = 0; mi < 4; mi++)
        a[mi] = *(const long*)&zt8[mi * 16 + l15][kk + q * 8];
      const unsigned char* wp = &W1B8[(size_t)(((kk >> 5) * 4 + q) * 256 + w * 64 + l15) * 8];
#pragma unroll
      for (int ni = 0; ni < 4; ni++)
        b[ni] = *(const long*)&wp[ni * 128];
#pragma unroll
      for (int mi = 0; mi < 4; mi++)
#pragma unroll
        for (int ni = 0; ni < 4; ni++)
          acc1[mi][ni] = __builtin_amdgcn_mfma_f32_16x16x32_fp8_fp8(a[mi], b[ni], acc1[mi][ni], 0, 0, 0);
    }
#pragma unroll
    for (int ni = 0; ni < 4; ni++) {
      int n = w * 64 + ni * 16 + l15;
      float bb = b1[n];
#pragma unroll
      for (int mi = 0; mi < 4; mi++)
#pragma unroll
        for (int r = 0; r < 4; r++) {
          float hv = acc1[mi][ni][r] + bb;
          hv = hv > 0.f ? hv : 0.f;
          int pk = __builtin_amdgcn_cvt_pk_fp8_f32(hv, hv, 0, false);
          hth8[mi * 16 + q * 4 + r][n] = (unsigned char)(pk & 0xff);
        }
    }
  }
  __syncthreads();

  // ---- G2 (fp8): acc2 = H @ W2; wave w owns cols [48w, 48w+48) ----
  f32x4 acc2[4][3];
#pragma unroll
  for (int mi = 0; mi < 4; mi++)
#pragma unroll
    for (int ni = 0; ni < 3; ni++) acc2[mi][ni] = z4;
#pragma unroll 2
  for (int kk = 0; kk < 256; kk += 32) {
    long a[4], b[3];
#pragma unroll
    for (int mi = 0; mi < 4; mi++)
      a[mi] = *(const long*)&hth8[mi * 16 + l15][kk + q * 8];
    const unsigned char* wp = &W2B8[(size_t)(((kk >> 5) * 4 + q) * 192 + w * 48 + l15) * 8];
#pragma unroll
    for (int ni = 0; ni < 3; ni++)
      b[ni] = *(const long*)&wp[ni * 128];
#pragma unroll
    for (int mi = 0; mi < 4; mi++)
#pragma unroll
      for (int ni = 0; ni < 3; ni++)
        acc2[mi][ni] = __builtin_amdgcn_mfma_f32_16x16x32_fp8_fp8(a[mi], b[ni], acc2[mi][ni], 0, 0, 0);
  }

  // ---- epilogue: v = z + acc2 + b2 -> fp8 in-place in zt8 (wave cols),
  // norms of the ROUNDED values pre-scaled by KL2E ----
  // Safe: all zt8 G1 A-reads completed at the post-G1 barrier; G2 reads hth8.
  {
    float nrm[4][4];
#pragma unroll
    for (int mi = 0; mi < 4; mi++)
#pragma unroll
      for (int r = 0; r < 4; r++) nrm[mi][r] = 0.f;
#pragma unroll
    for (int ni = 0; ni < 3; ni++) {
      int n = w * 48 + ni * 16 + l15;
      float bb = b2[n];
#pragma unroll
      for (int mi = 0; mi < 4; mi++)
#pragma unroll
        for (int r = 0; r < 4; r++) {
          int rr = mi * 16 + q * 4 + r;
          float zf = __builtin_amdgcn_cvt_f32_fp8((int)zt8[rr][n], 0);
          float v = zf + acc2[mi][ni][r] + bb;
          int pk = __builtin_amdgcn_cvt_pk_fp8_f32(v, v, 0, false);
          zt8[rr][n] = (unsigned char)(pk & 0xff);
          float vr = __builtin_amdgcn_cvt_f32_fp8(pk, 0);
          nrm[mi][r] += vr * vr;
        }
    }
#pragma unroll
    for (int mi = 0; mi < 4; mi++)
#pragma unroll
      for (int r = 0; r < 4; r++) {
        float s = nrm[mi][r];
        s += __shfl_xor(s, 1);
        s += __shfl_xor(s, 2);
        s += __shfl_xor(s, 4);
        s += __shfl_xor(s, 8);
        if (l15 == 0) atomicAdd(&n2l[mi * 16 + q * 4 + r], s);
      }
  }
  __syncthreads();

  // ---- copy-out (fp8) ----
  if (isq) {
    // queries: B-plane layout xe8[(p*512 + row)*8 + j]
    for (int cc = w; cc < 24; cc += 4) {
      long v = *(const long*)&zt8[lane][cc * 8];
      *(long*)&xe8[((size_t)cc * NQ + row0 + lane) * 8] = v;
    }
    if (t < 64) x2v[row0 + t] = n2l[t] * KL2E;
  } else {
    // candidates: row-major 192 B rows, coalesced uint copies
    unsigned int* dst = (unsigned int*)(ce8 + (size_t)row0 * DIM);
#pragma unroll
    for (int i = 0; i < 12; i++) {
      int j = t + 256 * i;                   // 0..3071 words
      int r = j / 48, cb = (j - r * 48) * 4;
      dst[j] = *(const unsigned int*)&zt8[r][cb];
    }
    if (t < 64) c2v[row0 + t] = n2l[t] * KL2E;
  }
}

// ---------------- K3: fp8 dist + exp2 + bf16 PV (v12, unchanged) --------
__global__ __launch_bounds__(256, 3) void k_dist(
    const unsigned char* __restrict__ xe8, const float* __restrict__ x2v,
    const unsigned char* __restrict__ ce8, const float* __restrict__ c2v,
    const bf16* __restrict__ YB, float* __restrict__ P) {
  __shared__ alignas(16) unsigned char ct8[64][208];  // 13.3 KB; P stage after
  __shared__ alignas(16) bf16 ET[4][16][72];          // per-wave exp tiles (9.2 KB)

  const int t = threadIdx.x;
  const int slice = blockIdx.x & (NSLICE - 1);
  const int half = blockIdx.x >> 9;
  const int n0 = slice * 256;
  const int qh = half * 256;
  const int lane = t & 63, w = t >> 6;
  const int l15 = lane & 15, q = lane >> 4;
  const int qbase = qh + w * 64;               // wave's 64 queries, fixed

  f32x4 z4 = {0.f, 0.f, 0.f, 0.f};
  f32x4 oacc[4];               // [nq] — compile-time indexed only
#pragma unroll
  for (int nq = 0; nq < 4; nq++) oacc[nq] = z4;

  // query norms (pre-scaled by KL2E) hoisted once
  float x2a[4];
#pragma unroll
  for (int nq = 0; nq < 4; nq++) x2a[nq] = x2v[qbase + nq * 16 + l15];

#pragma unroll 1
  for (int c = 0; c < 4; ++c) {
    if (c) __syncthreads();                    // prior compute's ct8 reads done
    {
      int sr = t >> 2, squ = t & 3;
      const uint4* src = (const uint4*)(ce8 + (size_t)(n0 + c * 64 + sr) * DIM + squ * 48);
      uint4* dst = (uint4*)&ct8[sr][squ * 48];
#pragma unroll
      for (int i = 0; i < 3; i++) dst[i] = src[i];
    }
    __syncthreads();

    // Y B-frags: pre-packed bf16, lane-contiguous
    bf16x8 yf[2];
#pragma unroll
    for (int kb = 0; kb < 2; kb++)
      yf[kb] = *(const bf16x8*)&YB[((size_t)((slice * 8) + c * 2 + kb) * 64 + lane) * 8];
    // candidate norms (pre-scaled): broadcast f32x4 loads
    f32x4 c2r[4];
#pragma unroll
    for (int mc = 0; mc < 4; mc++)
      c2r[mc] = *(const f32x4*)&c2v[n0 + c * 64 + mc * 16 + q * 4];

    // single fp8 dist-GEMM pass: 64 cands x 64 queries
    f32x4 acc[4][4];           // [mc][nq]
#pragma unroll
    for (int mc = 0; mc < 4; mc++)
#pragma unroll
      for (int nq = 0; nq < 4; nq++) acc[mc][nq] = z4;

#pragma unroll 1
    for (int kk = 0; kk < 192; kk += 32) {
      long a[4], b[4];
#pragma unroll
      for (int mc = 0; mc < 4; mc++)
        a[mc] = *(const long*)&ct8[mc * 16 + l15][kk + q * 8];
      const unsigned char* xp = &xe8[(size_t)(((kk >> 5) * 4 + q) * NQ + qbase + l15) * 8];
#pragma unroll
      for (int nq = 0; nq < 4; nq++)
        b[nq] = *(const long*)&xp[nq * 128];
#pragma unroll
      for (int mc = 0; mc < 4; mc++)
#pragma unroll
        for (int nq = 0; nq < 4; nq++)
          acc[mc][nq] = __builtin_amdgcn_mfma_f32_16x16x32_fp8_fp8(a[mc], b[nq], acc[mc][nq], 0, 0, 0);
    }

    // epilogue: e = exp2(-sqrt(|K*d2|)) = exp(-dist); ET -> PV MFMA
#pragma unroll
    for (int nq = 0; nq < 4; ++nq) {
#pragma unroll
      for (int mc = 0; mc < 4; mc++) {
        bf16x4 ev;
#pragma unroll
        for (int r = 0; r < 4; r++) {
          float d2 = __builtin_fmaf(N2KL2E, acc[mc][nq][r], x2a[nq] + c2r[mc][r]);
          ev[r] = (bf16)__builtin_amdgcn_exp2f(-__builtin_amdgcn_sqrtf(__builtin_fabsf(d2)));
        }
        *(bf16x4*)&ET[w][l15][mc * 16 + q * 4] = ev;
      }
#pragma unroll
      for (int kb = 0; kb < 2; kb++) {
        bf16x8 a = *(const bf16x8*)&ET[w][l15][kb * 32 + q * 8];
        oacc[nq] = __builtin_amdgcn_mfma_f32_16x16x32_bf16(a, yf[kb], oacc[nq], 0, 0, 0);
      }
    }
  }

  // ---- dense P write: stage in LDS (ct8 is dead), contiguous f32x4 ----
  __syncthreads();
  float* Pst = (float*)&ct8[0][0];             // 256 q x 12 = 12.3 KB
  if (l15 < 11) {
#pragma unroll
    for (int nq = 0; nq < 4; nq++)
#pragma unroll
      for (int r = 0; r < 4; r++) {
        int lq = w * 64 + nq * 16 + q * 4 + r;
        Pst[lq * 12 + l15] = oacc[nq][r];
      }
  }
  __syncthreads();
  {
    f32x4* Pg = (f32x4*)(P + (size_t)blockIdx.x * 3072);   // 256*12 floats
    const f32x4* Ps = (const f32x4*)Pst;
#pragma unroll
    for (int i = t; i < 768; i += 256) Pg[i] = Ps[i];
  }
}

// ---------------- K4: combine (pure sum — no max needed) ----------------
__global__ __launch_bounds__(512) void k_comb(const float* __restrict__ P,
                                              float* __restrict__ out) {
  __shared__ float red[8][11];
  const int t = threadIdx.x;
  const int qy = blockIdx.x;
  const int lane = t & 63, w = t >> 6;

  // record for (block = half*512 + slice, localq = qy&255); slice = t
  const float* p = &P[((size_t)((qy >> 8) * 512 + t) * 256 + (qy & 255)) * 12];
  f32x4 v0 = *(const f32x4*)&p[0];
  f32x4 v1 = *(const f32x4*)&p[4];
  f32x4 v2 = *(const f32x4*)&p[8];
  float s[11];
#pragma unroll
  for (int j = 0; j < 4; j++) s[j] = v0[j];
#pragma unroll
  for (int j = 0; j < 4; j++) s[4 + j] = v1[j];
#pragma unroll
  for (int j = 0; j < 3; j++) s[8 + j] = v2[j];
#pragma unroll
  for (int d = 1; d < 64; d <<= 1)
#pragma unroll
    for (int j = 0; j < 11; j++) s[j] += __shfl_xor(s[j], d);
  if (lane == 0)
#pragma unroll
    for (int j = 0; j < 11; j++) red[w][j] = s[j];
  __syncthreads();
  if (t < 10) {
    float o = 0.f, l = 0.f;
#pragma unroll
    for (int i = 0; i < 8; i++) { o += red[i][t]; l += red[i][10]; }
    out[qy * NY + t] = o / l;
  }
}

// ---------------- launcher ----------------
extern "C" void kernel_launch(void* const* d_in, const int* in_sizes, int n_in,
                              void* d_out, int out_size, void* d_ws, size_t ws_size,
                              hipStream_t stream) {
  (void)in_sizes; (void)n_in; (void)out_size; (void)ws_size;
  const float* x_num = (const float*)d_in[0];
  const int*   x_cat = (const int*)d_in[1];
  const float* c_num = (const float*)d_in[2];
  const int*   c_cat = (const int*)d_in[3];
  const float* c_y   = (const float*)d_in[4];
  const float* W_num = (const float*)d_in[5];
  const float* b_num = (const float*)d_in[6];
  const float* emb   = (const float*)d_in[7];
  const float* W1    = (const float*)d_in[8];
  const float* b1    = (const float*)d_in[9];
  const float* W2    = (const float*)d_in[10];
  const float* b2    = (const float*)d_in[11];
  float* out = (float*)d_out;

  char* ws = (char*)d_ws;
  unsigned char* W1B8 = (unsigned char*)(ws + OFF_W1B);
  unsigned char* W2B8 = (unsigned char*)(ws + OFF_W2B);
  unsigned char* xe8  = (unsigned char*)(ws + OFF_XE8);
  float* x2v = (float*)(ws + OFF_X2);
  unsigned char* ce8  = (unsigned char*)(ws + OFF_CE8);
  float* c2v = (float*)(ws + OFF_C2);
  float* P   = (float*)(ws + OFF_P);
  bf16*  YB  = (bf16*)(ws + OFF_YB);

  k_prep<<<dim3(1408), dim3(256), 0, stream>>>(W1, W2, c_y, W1B8, W2B8, YB);
  k_encode<<<dim3(8 + NC / 64), dim3(256), 0, stream>>>(
      x_num, x_cat, c_num, c_cat, W_num, b_num, emb, b1, b2, W1B8, W2B8,
      ce8, xe8, x2v, c2v);
  k_dist<<<dim3(2 * NSLICE), dim3(256), 0, stream>>>(xe8, x2v, ce8, c2v, YB, P);
  k_comb<<<dim3(NQ), dim3(512), 0, stream>>>(P, out);
}